// Round 1
// baseline (20609.869 us; speedup 1.0000x reference)
//
#include <hip/hip_runtime.h>

// Problem constants
#define B_   16
#define C_   512
#define T_   1024
#define H_   8
#define D_   64
#define G_   32
#define L_   77
#define S_   1101          // T + L
#define CD_  768
#define BT_  (B_*T_)       // 16384
#define BL_  (B_*L_)       // 1232

// ---------------- GroupNorm statistics ----------------
// One block per (b, g): 16 channels x 1024 spatial = 16384 contiguous floats.
__global__ __launch_bounds__(256) void gn_stats_k(const float* __restrict__ x,
                                                  float* __restrict__ stats) {
    const int bg = blockIdx.x;                 // b*32 + g
    const float* p = x + (size_t)bg * 16384;
    const int tid = threadIdx.x;
    float s = 0.f, s2 = 0.f;
    for (int i = tid; i < 16384; i += 256) {
        float v = p[i];
        s += v; s2 += v * v;
    }
    __shared__ float rs[256], rs2[256];
    rs[tid] = s; rs2[tid] = s2;
    __syncthreads();
    for (int off = 128; off > 0; off >>= 1) {
        if (tid < off) { rs[tid] += rs[tid + off]; rs2[tid] += rs2[tid + off]; }
        __syncthreads();
    }
    if (tid == 0) {
        float mean = rs[0] * (1.0f / 16384.0f);
        float var  = rs2[0] * (1.0f / 16384.0f) - mean * mean;
        stats[2 * bg]     = mean;
        stats[2 * bg + 1] = rsqrtf(var + 1e-5f);
    }
}

// ---------------- Normalize + transpose to xn[c, b, t] ----------------
__global__ __launch_bounds__(256) void gn_apply_k(const float* __restrict__ x,
                                                  const float* __restrict__ stats,
                                                  const float* __restrict__ gamma,
                                                  const float* __restrict__ beta,
                                                  float* __restrict__ xn) {
    const int i4 = blockIdx.x * 256 + threadIdx.x;   // over B*C*T/4 = 2097152
    if (i4 >= (B_ * C_ * T_) / 4) return;
    const int idx = i4 * 4;
    const int b   = idx >> 19;                 // / (C*T)
    const int rem = idx & ((1 << 19) - 1);
    const int c   = rem >> 10;                 // / T
    const int t   = rem & 1023;
    float4 xv = ((const float4*)x)[i4];
    const int bg = b * G_ + (c >> 4);
    const float mean = stats[2 * bg], istd = stats[2 * bg + 1];
    const float gs = gamma[c] * istd;
    const float gb = beta[c] - mean * gs;
    float4 o;
    o.x = xv.x * gs + gb; o.y = xv.y * gs + gb;
    o.z = xv.z * gs + gb; o.w = xv.w * gs + gb;
    *(float4*)(xn + ((size_t)(c * B_ + b) << 10) + t) = o;
}

// ---------------- Generic tiled SGEMM ----------------
// C[m,n] = sum_k A[m,k] * B[k,n] (+bias[m]) (+resid), batched on blockIdx.z.
// A is M x K row-major (shared across batch). B per batch: ldb row stride.
// K must be a multiple of 8.
__global__ __launch_bounds__(256) void gemm_k(const float* __restrict__ A,
                                              const float* __restrict__ Bm,
                                              float* __restrict__ Cm,
                                              const float* __restrict__ bias,
                                              const float* __restrict__ resid,
                                              int M, int N, int K, int ldb, int ldc,
                                              long long strideB, long long strideC) {
    __shared__ float As[8][128];   // [k][m]
    __shared__ float Bs[8][128];   // [k][n]
    const int tid = threadIdx.x;
    const int m0 = blockIdx.y * 128, n0 = blockIdx.x * 128;
    const float* Bb = Bm + (long long)blockIdx.z * strideB;
    float* Cb = Cm + (long long)blockIdx.z * strideC;
    const float* Rb = resid ? (resid + (long long)blockIdx.z * strideC) : nullptr;

    const int tx = tid & 15, ty = tid >> 4;
    const int arow = tid >> 1, acol = (tid & 1) * 4;
    const int brow = tid >> 5, bcol = (tid & 31) * 4;

    float acc[8][8];
#pragma unroll
    for (int i = 0; i < 8; i++)
#pragma unroll
        for (int j = 0; j < 8; j++) acc[i][j] = 0.f;

    for (int k0 = 0; k0 < K; k0 += 8) {
        float a0 = 0, a1 = 0, a2 = 0, a3 = 0;
        if (m0 + arow < M) {
            const float* ap = A + (size_t)(m0 + arow) * K + k0 + acol;
            a0 = ap[0]; a1 = ap[1]; a2 = ap[2]; a3 = ap[3];
        }
        float b0 = 0, b1 = 0, b2 = 0, b3 = 0;
        {
            const float* bp = Bb + (size_t)(k0 + brow) * ldb + n0 + bcol;
            const int nrem = N - (n0 + bcol);
            if (nrem >= 4) { b0 = bp[0]; b1 = bp[1]; b2 = bp[2]; b3 = bp[3]; }
            else {
                if (nrem > 0) b0 = bp[0];
                if (nrem > 1) b1 = bp[1];
                if (nrem > 2) b2 = bp[2];
            }
        }
        __syncthreads();
        As[acol + 0][arow] = a0; As[acol + 1][arow] = a1;
        As[acol + 2][arow] = a2; As[acol + 3][arow] = a3;
        *(float4*)&Bs[brow][bcol] = make_float4(b0, b1, b2, b3);
        __syncthreads();
#pragma unroll
        for (int kk = 0; kk < 8; kk++) {
            float4 av0 = *(const float4*)&As[kk][ty * 8];
            float4 av1 = *(const float4*)&As[kk][ty * 8 + 4];
            float4 bv0 = *(const float4*)&Bs[kk][tx * 8];
            float4 bv1 = *(const float4*)&Bs[kk][tx * 8 + 4];
            float am[8] = {av0.x, av0.y, av0.z, av0.w, av1.x, av1.y, av1.z, av1.w};
            float bn[8] = {bv0.x, bv0.y, bv0.z, bv0.w, bv1.x, bv1.y, bv1.z, bv1.w};
#pragma unroll
            for (int i = 0; i < 8; i++)
#pragma unroll
                for (int j = 0; j < 8; j++) acc[i][j] += am[i] * bn[j];
        }
    }
#pragma unroll
    for (int i = 0; i < 8; i++) {
        const int cm = m0 + ty * 8 + i;
        if (cm < M) {
            const float bv = bias ? bias[cm] : 0.f;
#pragma unroll
            for (int j = 0; j < 8; j++) {
                const int cn = n0 + tx * 8 + j;
                if (cn < N) {
                    const size_t off = (size_t)cm * ldc + cn;
                    float v = acc[i][j] + bv;
                    if (Rb) v += Rb[off];
                    Cb[off] = v;
                }
            }
        }
    }
}

// ---------------- V transpose: vT[(bh*S + s)*64 + c] ----------------
__global__ __launch_bounds__(256) void build_vT_k(const float* __restrict__ qkv,
                                                  const float* __restrict__ ckv,
                                                  float* __restrict__ vT) {
    const int s0 = blockIdx.x * 64;
    const int bh = blockIdx.y;
    const int b = bh >> 3, h = bh & 7;
    const int tid = threadIdx.x;
    __shared__ float tile[64][65];
    const int sl = tid & 63, rr = tid >> 6;
    const int s = s0 + sl;
#pragma unroll
    for (int cb = 0; cb < 64; cb += 4) {
        const int c = cb + rr;
        float v = 0.f;
        if (s < S_) {
            if (s < T_) v = qkv[(size_t)(2 * C_ + h * 64 + c) * BT_ + (size_t)b * T_ + s];
            else        v = ckv[(size_t)(C_ + h * 64 + c) * BL_ + (size_t)b * L_ + (s - T_)];
        }
        tile[sl][c] = v;
    }
    __syncthreads();
    const int cl = tid & 63;
#pragma unroll
    for (int sb = 0; sb < 64; sb += 4) {
        const int sr = sb + rr;
        const int ss = s0 + sr;
        if (ss < S_) vT[((size_t)bh * S_ + ss) * 64 + cl] = tile[sr][cl];
    }
}

// ---------------- Attention: 4 query rows per block ----------------
__global__ __launch_bounds__(256) void attn_k(const float* __restrict__ qkv,
                                              const float* __restrict__ ckv,
                                              const float* __restrict__ vT,
                                              float* __restrict__ abuf) {
    const int t0 = blockIdx.x * 4;
    const int bh = blockIdx.y;
    const int b = bh >> 3, h = bh & 7;
    const int tid = threadIdx.x;

    __shared__ float qs[4][64];
    __shared__ float sc[4][1104];
    __shared__ float4 red[256];
    __shared__ float part[4][4][64];

    {
        const int r = tid >> 6, c = tid & 63;
        qs[r][c] = qkv[(size_t)(h * 64 + c) * BT_ + (size_t)b * T_ + (t0 + r)];
    }
    __syncthreads();

    float m0v = -1e30f, m1v = -1e30f, m2v = -1e30f, m3v = -1e30f;
    for (int s = tid; s < S_; s += 256) {
        float d0 = 0, d1 = 0, d2 = 0, d3 = 0;
        if (s < T_) {
            const float* kc = qkv + (size_t)(C_ + h * 64) * BT_ + (size_t)b * T_ + s;
#pragma unroll
            for (int c = 0; c < 64; c++) {
                const float kv = kc[(size_t)c * BT_];
                d0 += qs[0][c] * kv; d1 += qs[1][c] * kv;
                d2 += qs[2][c] * kv; d3 += qs[3][c] * kv;
            }
        } else {
            const float* kc = ckv + (size_t)(h * 64) * BL_ + (size_t)b * L_ + (s - T_);
#pragma unroll
            for (int c = 0; c < 64; c++) {
                const float kv = kc[(size_t)c * BL_];
                d0 += qs[0][c] * kv; d1 += qs[1][c] * kv;
                d2 += qs[2][c] * kv; d3 += qs[3][c] * kv;
            }
        }
        d0 *= 0.125f; d1 *= 0.125f; d2 *= 0.125f; d3 *= 0.125f;
        sc[0][s] = d0; sc[1][s] = d1; sc[2][s] = d2; sc[3][s] = d3;
        m0v = fmaxf(m0v, d0); m1v = fmaxf(m1v, d1);
        m2v = fmaxf(m2v, d2); m3v = fmaxf(m3v, d3);
    }
    red[tid] = make_float4(m0v, m1v, m2v, m3v);
    __syncthreads();
    for (int off = 128; off > 0; off >>= 1) {
        if (tid < off) {
            float4 a = red[tid], bb = red[tid + off];
            red[tid] = make_float4(fmaxf(a.x, bb.x), fmaxf(a.y, bb.y),
                                   fmaxf(a.z, bb.z), fmaxf(a.w, bb.w));
        }
        __syncthreads();
    }
    const float4 mx = red[0];
    __syncthreads();

    float l0 = 0, l1 = 0, l2 = 0, l3 = 0;
    for (int s = tid; s < S_; s += 256) {
        float e0 = __expf(sc[0][s] - mx.x); sc[0][s] = e0; l0 += e0;
        float e1 = __expf(sc[1][s] - mx.y); sc[1][s] = e1; l1 += e1;
        float e2 = __expf(sc[2][s] - mx.z); sc[2][s] = e2; l2 += e2;
        float e3 = __expf(sc[3][s] - mx.w); sc[3][s] = e3; l3 += e3;
    }
    red[tid] = make_float4(l0, l1, l2, l3);
    __syncthreads();
    for (int off = 128; off > 0; off >>= 1) {
        if (tid < off) {
            float4 a = red[tid], bb = red[tid + off];
            red[tid] = make_float4(a.x + bb.x, a.y + bb.y, a.z + bb.z, a.w + bb.w);
        }
        __syncthreads();
    }
    const float4 lv = red[0];

    // Phase 2: P @ V using vT (coalesced in c across lanes)
    const int c = tid & 63, chunk = tid >> 6;
    const int sb = chunk * 276;
    const int se = min(S_, sb + 276);
    const float* vb = vT + (size_t)bh * S_ * 64 + c;
    float a0 = 0, a1 = 0, a2 = 0, a3 = 0;
    for (int s = sb; s < se; s++) {
        const float vv = vb[(size_t)s * 64];
        a0 += sc[0][s] * vv; a1 += sc[1][s] * vv;
        a2 += sc[2][s] * vv; a3 += sc[3][s] * vv;
    }
    part[0][chunk][c] = a0; part[1][chunk][c] = a1;
    part[2][chunk][c] = a2; part[3][chunk][c] = a3;
    __syncthreads();
    {
        const int cw = tid >> 2, rw = tid & 3;
        const float sum = part[rw][0][cw] + part[rw][1][cw] +
                          part[rw][2][cw] + part[rw][3][cw];
        const float l = (rw == 0) ? lv.x : (rw == 1) ? lv.y : (rw == 2) ? lv.z : lv.w;
        abuf[(size_t)(h * 64 + cw) * BT_ + (size_t)b * T_ + t0 + rw] = sum / l;
    }
}

// ---------------- Launch ----------------
extern "C" void kernel_launch(void* const* d_in, const int* in_sizes, int n_in,
                              void* d_out, int out_size, void* d_ws, size_t ws_size,
                              hipStream_t stream) {
    const float* x     = (const float*)d_in[0];
    const float* cin   = (const float*)d_in[1];
    const float* gamma = (const float*)d_in[2];
    const float* beta  = (const float*)d_in[3];
    const float* w_qkv = (const float*)d_in[4];
    const float* b_qkv = (const float*)d_in[5];
    const float* w_c   = (const float*)d_in[6];
    const float* b_c   = (const float*)d_in[7];
    const float* w_p   = (const float*)d_in[8];
    const float* b_p   = (const float*)d_in[9];
    float* out = (float*)d_out;

    float* ws    = (float*)d_ws;
    float* stats = ws;                       // 1024 floats
    float* xn    = ws + 1024;                // 8,388,608 (reused as attention out 'a')
    float* qkv   = xn + 8388608;             // 25,165,824
    float* ckv   = qkv + 25165824;           // 1,261,568
    float* vT    = ckv + 1261568;            // 9,019,392
    // total: ~167.2 MiB of workspace

    // 1. GroupNorm stats
    gn_stats_k<<<dim3(B_ * G_), 256, 0, stream>>>(x, stats);
    // 2. Normalize + transpose to xn[c, b*t]
    gn_apply_k<<<dim3((B_ * C_ * T_) / 4 / 256), 256, 0, stream>>>(x, stats, gamma, beta, xn);
    // 3. qkv = w_qkv(1536x512) @ xn(512x16384) + b_qkv
    gemm_k<<<dim3(128, 12, 1), 256, 0, stream>>>(w_qkv, xn, qkv, b_qkv, nullptr,
                                                 1536, BT_, C_, BT_, BT_, 0, 0);
    // 4. ckv = w_c(1024x768) @ c_b(768x77) + b_c, batched over b; out ckv[o, b, l]
    gemm_k<<<dim3(1, 8, B_), 256, 0, stream>>>(w_c, cin, ckv, b_c, nullptr,
                                               1024, L_, CD_, L_, BL_,
                                               (long long)CD_ * L_, L_);
    // 5. V transpose
    build_vT_k<<<dim3((S_ + 63) / 64, B_ * H_), 256, 0, stream>>>(qkv, ckv, vT);
    // 6. Attention -> a[o, b, t] (reuses xn buffer)
    attn_k<<<dim3(T_ / 4, B_ * H_), 256, 0, stream>>>(qkv, ckv, vT, xn);
    // 7. out = w_p(512x512) @ a_b(512x1024) + b_p + x, batched over b
    gemm_k<<<dim3(8, 4, B_), 256, 0, stream>>>(w_p, xn, out, b_p, x,
                                               C_, T_, C_, BT_, T_,
                                               (long long)T_, (long long)C_ * T_);
}

// Round 2
// 896.824 us; speedup vs baseline: 22.9810x; 22.9810x over previous
//
#include <hip/hip_runtime.h>

// Problem constants
#define B_   16
#define C_   512
#define T_   1024
#define H_   8
#define D_   64
#define G_   32
#define L_   77
#define S_   1101          // T + L
#define SPAD 1152          // padded S (multiple of 64)
#define CD_  768
#define BT_  (B_*T_)       // 16384
#define BL_  (B_*L_)       // 1232
#define KROW 72            // LDS row stride in bf16 elems (64 + 8 pad)

typedef __bf16 bf16x8 __attribute__((ext_vector_type(8)));
typedef float  f32x4  __attribute__((ext_vector_type(4)));

static __device__ __forceinline__ unsigned short f2bf(float f) {
    unsigned int u = __float_as_uint(f);
    u = (u + 0x7fffu + ((u >> 16) & 1u)) >> 16;
    return (unsigned short)u;
}

// ---------------- GroupNorm statistics ----------------
__global__ __launch_bounds__(256) void gn_stats_k(const float* __restrict__ x,
                                                  float* __restrict__ stats) {
    const int bg = blockIdx.x;
    const float* p = x + (size_t)bg * 16384;
    const int tid = threadIdx.x;
    float s = 0.f, s2 = 0.f;
    for (int i = tid; i < 16384; i += 256) {
        float v = p[i];
        s += v; s2 += v * v;
    }
    __shared__ float rs[256], rs2[256];
    rs[tid] = s; rs2[tid] = s2;
    __syncthreads();
    for (int off = 128; off > 0; off >>= 1) {
        if (tid < off) { rs[tid] += rs[tid + off]; rs2[tid] += rs2[tid + off]; }
        __syncthreads();
    }
    if (tid == 0) {
        float mean = rs[0] * (1.0f / 16384.0f);
        float var  = rs2[0] * (1.0f / 16384.0f) - mean * mean;
        stats[2 * bg]     = mean;
        stats[2 * bg + 1] = rsqrtf(var + 1e-5f);
    }
}

// ---------------- Normalize + transpose to xn[c, b, t] ----------------
__global__ __launch_bounds__(256) void gn_apply_k(const float* __restrict__ x,
                                                  const float* __restrict__ stats,
                                                  const float* __restrict__ gamma,
                                                  const float* __restrict__ beta,
                                                  float* __restrict__ xn) {
    const int i4 = blockIdx.x * 256 + threadIdx.x;
    if (i4 >= (B_ * C_ * T_) / 4) return;
    const int idx = i4 * 4;
    const int b   = idx >> 19;
    const int rem = idx & ((1 << 19) - 1);
    const int c   = rem >> 10;
    const int t   = rem & 1023;
    float4 xv = ((const float4*)x)[i4];
    const int bg = b * G_ + (c >> 4);
    const float mean = stats[2 * bg], istd = stats[2 * bg + 1];
    const float gs = gamma[c] * istd;
    const float gb = beta[c] - mean * gs;
    float4 o;
    o.x = xv.x * gs + gb; o.y = xv.y * gs + gb;
    o.z = xv.z * gs + gb; o.w = xv.w * gs + gb;
    *(float4*)(xn + ((size_t)(c * B_ + b) << 10) + t) = o;
}

// ---------------- Generic tiled SGEMM (fp32, vector ALU) ----------------
__global__ __launch_bounds__(256) void gemm_k(const float* __restrict__ A,
                                              const float* __restrict__ Bm,
                                              float* __restrict__ Cm,
                                              const float* __restrict__ bias,
                                              const float* __restrict__ resid,
                                              int M, int N, int K, int ldb, int ldc,
                                              long long strideB, long long strideC) {
    __shared__ float As[8][128];
    __shared__ float Bs[8][128];
    const int tid = threadIdx.x;
    const int m0 = blockIdx.y * 128, n0 = blockIdx.x * 128;
    const float* Bb = Bm + (long long)blockIdx.z * strideB;
    float* Cb = Cm + (long long)blockIdx.z * strideC;
    const float* Rb = resid ? (resid + (long long)blockIdx.z * strideC) : nullptr;

    const int tx = tid & 15, ty = tid >> 4;
    const int arow = tid >> 1, acol = (tid & 1) * 4;
    const int brow = tid >> 5, bcol = (tid & 31) * 4;

    float acc[8][8];
#pragma unroll
    for (int i = 0; i < 8; i++)
#pragma unroll
        for (int j = 0; j < 8; j++) acc[i][j] = 0.f;

    for (int k0 = 0; k0 < K; k0 += 8) {
        float a0 = 0, a1 = 0, a2 = 0, a3 = 0;
        if (m0 + arow < M) {
            const float* ap = A + (size_t)(m0 + arow) * K + k0 + acol;
            a0 = ap[0]; a1 = ap[1]; a2 = ap[2]; a3 = ap[3];
        }
        float b0 = 0, b1 = 0, b2 = 0, b3 = 0;
        {
            const float* bp = Bb + (size_t)(k0 + brow) * ldb + n0 + bcol;
            const int nrem = N - (n0 + bcol);
            if (nrem >= 4) { b0 = bp[0]; b1 = bp[1]; b2 = bp[2]; b3 = bp[3]; }
            else {
                if (nrem > 0) b0 = bp[0];
                if (nrem > 1) b1 = bp[1];
                if (nrem > 2) b2 = bp[2];
            }
        }
        __syncthreads();
        As[acol + 0][arow] = a0; As[acol + 1][arow] = a1;
        As[acol + 2][arow] = a2; As[acol + 3][arow] = a3;
        *(float4*)&Bs[brow][bcol] = make_float4(b0, b1, b2, b3);
        __syncthreads();
#pragma unroll
        for (int kk = 0; kk < 8; kk++) {
            float4 av0 = *(const float4*)&As[kk][ty * 8];
            float4 av1 = *(const float4*)&As[kk][ty * 8 + 4];
            float4 bv0 = *(const float4*)&Bs[kk][tx * 8];
            float4 bv1 = *(const float4*)&Bs[kk][tx * 8 + 4];
            float am[8] = {av0.x, av0.y, av0.z, av0.w, av1.x, av1.y, av1.z, av1.w};
            float bn[8] = {bv0.x, bv0.y, bv0.z, bv0.w, bv1.x, bv1.y, bv1.z, bv1.w};
#pragma unroll
            for (int i = 0; i < 8; i++)
#pragma unroll
                for (int j = 0; j < 8; j++) acc[i][j] += am[i] * bn[j];
        }
    }
#pragma unroll
    for (int i = 0; i < 8; i++) {
        const int cm = m0 + ty * 8 + i;
        if (cm < M) {
            const float bv = bias ? bias[cm] : 0.f;
#pragma unroll
            for (int j = 0; j < 8; j++) {
                const int cn = n0 + tx * 8 + j;
                if (cn < N) {
                    const size_t off = (size_t)cm * ldc + cn;
                    float v = acc[i][j] + bv;
                    if (Rb) v += Rb[off];
                    Cb[off] = v;
                }
            }
        }
    }
}

// ---------------- Pack Q and K to bf16, token-major [bh][tok][64] ----------------
// z=0: Q (16 tiles of 64 rows), z=1: K (18 tiles incl. cross + zero pad)
__global__ __launch_bounds__(256) void pack_qk_k(const float* __restrict__ qkv,
                                                 const float* __restrict__ ckv,
                                                 unsigned short* __restrict__ qb2,
                                                 unsigned short* __restrict__ kb2) {
    const int isK  = blockIdx.z;
    const int tile = blockIdx.x;
    if (!isK && tile >= 16) return;
    const int bh = blockIdx.y;
    const int b = bh >> 3, h = bh & 7;
    __shared__ float tb[64][65];
    const int tid = threadIdx.x;
    const int sl = tid & 63, rr = tid >> 6;
    const int tok = tile * 64 + sl;
    const int off = isK ? C_ : 0;
#pragma unroll
    for (int cb = 0; cb < 64; cb += 4) {
        const int ch = cb + rr;
        float v = 0.f;
        if (tok < T_)            v = qkv[(size_t)(off + h * 64 + ch) * BT_ + (size_t)b * T_ + tok];
        else if (isK && tok < S_) v = ckv[(size_t)(h * 64 + ch) * BL_ + (size_t)b * L_ + (tok - T_)];
        tb[sl][ch] = v;
    }
    __syncthreads();
    const int cl = tid & 63;
    unsigned short* dst = isK ? (kb2 + (size_t)bh * SPAD * 64)
                              : (qb2 + (size_t)bh * 1024 * 64);
#pragma unroll
    for (int sb = 0; sb < 64; sb += 4) {
        const int sr = sb + rr;
        dst[((size_t)(tile * 64 + sr)) * 64 + cl] = f2bf(tb[sr][cl]);
    }
}

// ---------------- Pack V to bf16, channel-major [bh][ch][SPAD] ----------------
__global__ __launch_bounds__(256) void pack_v_k(const float* __restrict__ qkv,
                                                const float* __restrict__ ckv,
                                                unsigned short* __restrict__ vb2) {
    const int bh = blockIdx.y;
    const int b = bh >> 3, h = bh & 7;
    const int tid = threadIdx.x;
    const int s = blockIdx.x * 64 + (tid & 63);
    const int rr = tid >> 6;
#pragma unroll
    for (int cb = 0; cb < 64; cb += 4) {
        const int ch = cb + rr;
        float v = 0.f;
        if (s < T_)      v = qkv[(size_t)(2 * C_ + h * 64 + ch) * BT_ + (size_t)b * T_ + s];
        else if (s < S_) v = ckv[(size_t)(C_ + h * 64 + ch) * BL_ + (size_t)b * L_ + (s - T_)];
        vb2[((size_t)bh * 64 + ch) * SPAD + s] = f2bf(v);
    }
}

// ---------------- Flash attention, MFMA bf16 16x16x32 ----------------
// Grid (T/64, B*H); 4 waves/WG; wave w owns Q rows [qt0 + w*16, +16).
__global__ __launch_bounds__(256) void flash_k(const unsigned short* __restrict__ qb,
                                               const unsigned short* __restrict__ kb,
                                               const unsigned short* __restrict__ vb,
                                               float* __restrict__ abuf) {
    __shared__ __align__(16) unsigned short qs[64 * KROW];
    __shared__ __align__(16) unsigned short ks[64 * KROW];
    __shared__ __align__(16) unsigned short vs[64 * KROW];
    __shared__ __align__(16) unsigned short ps[4][16 * KROW];

    const int tid  = threadIdx.x;
    const int wave = tid >> 6, lane = tid & 63;
    const int quad = lane >> 4, l16 = lane & 15;
    const int bh  = blockIdx.y;
    const int b = bh >> 3, h = bh & 7;
    const int qt0 = blockIdx.x * 64;

    // ---- stage Q tile (64 rows x 64 ch) ----
    {
        const int row = tid >> 2, col = (tid & 3) * 16;
        const unsigned short* src = qb + ((size_t)bh * 1024 + qt0) * 64;
        *(uint4*)&qs[row * KROW + col]     = *(const uint4*)&src[row * 64 + col];
        *(uint4*)&qs[row * KROW + col + 8] = *(const uint4*)&src[row * 64 + col + 8];
    }
    __syncthreads();

    // Q A-frags: m = l16 (row wave*16+l16), k = quad*8+j (+32)
    const int qrow = wave * 16 + l16;
    const bf16x8 aq0 = *(const bf16x8*)&qs[qrow * KROW + quad * 8];
    const bf16x8 aq1 = *(const bf16x8*)&qs[qrow * KROW + 32 + quad * 8];

    float m_i[4], l_i[4];
    f32x4 o_acc[4];
#pragma unroll
    for (int r = 0; r < 4; r++) { m_i[r] = -1e30f; l_i[r] = 0.f; }
#pragma unroll
    for (int nb = 0; nb < 4; nb++) o_acc[nb] = (f32x4){0.f, 0.f, 0.f, 0.f};

    for (int s0 = 0; s0 < SPAD; s0 += 64) {
        __syncthreads();
        // ---- stage K (s-major) and V (ch-major) tiles ----
        {
            const int row = tid >> 2, col = (tid & 3) * 16;
            const unsigned short* ksrc = kb + ((size_t)bh * SPAD + s0 + row) * 64;
            *(uint4*)&ks[row * KROW + col]     = *(const uint4*)&ksrc[col];
            *(uint4*)&ks[row * KROW + col + 8] = *(const uint4*)&ksrc[col + 8];
            const unsigned short* vsrc = vb + ((size_t)bh * 64 + row) * SPAD + s0;
            *(uint4*)&vs[row * KROW + col]     = *(const uint4*)&vsrc[col];
            *(uint4*)&vs[row * KROW + col + 8] = *(const uint4*)&vsrc[col + 8];
        }
        __syncthreads();

        // ---- QK^T: 4 col-blocks of 16 ----
        f32x4 sacc[4];
#pragma unroll
        for (int cb = 0; cb < 4; cb++) {
            const bf16x8 bk0 = *(const bf16x8*)&ks[(cb * 16 + l16) * KROW + quad * 8];
            const bf16x8 bk1 = *(const bf16x8*)&ks[(cb * 16 + l16) * KROW + 32 + quad * 8];
            f32x4 z = (f32x4){0.f, 0.f, 0.f, 0.f};
            z = __builtin_amdgcn_mfma_f32_16x16x32_bf16(aq0, bk0, z, 0, 0, 0);
            z = __builtin_amdgcn_mfma_f32_16x16x32_bf16(aq1, bk1, z, 0, 0, 0);
            sacc[cb] = z;
        }

        // ---- scale + mask ----
        float p[4][4];
#pragma unroll
        for (int cb = 0; cb < 4; cb++) {
            const bool valid = (s0 + cb * 16 + l16) < S_;
#pragma unroll
            for (int r = 0; r < 4; r++)
                p[cb][r] = valid ? sacc[cb][r] * 0.125f : -1e30f;
        }

        // ---- row max (reduce over 16 lanes of quad) ----
        float rm[4], alpha[4];
#pragma unroll
        for (int r = 0; r < 4; r++) {
            float m = fmaxf(fmaxf(p[0][r], p[1][r]), fmaxf(p[2][r], p[3][r]));
#pragma unroll
            for (int off = 1; off < 16; off <<= 1) m = fmaxf(m, __shfl_xor(m, off));
            rm[r] = m;
        }
#pragma unroll
        for (int r = 0; r < 4; r++) {
            const float mo = m_i[r];
            const float mn = fmaxf(mo, rm[r]);
            m_i[r] = mn;
            alpha[r] = __expf(mo - mn);
            l_i[r] *= alpha[r];
        }

        // ---- exp, P->bf16 into per-wave LDS (A layout rows 0..15), row sums ----
        float rsum[4] = {0.f, 0.f, 0.f, 0.f};
#pragma unroll
        for (int cb = 0; cb < 4; cb++) {
#pragma unroll
            for (int r = 0; r < 4; r++) {
                const float e = __expf(p[cb][r] - m_i[r]);
                rsum[r] += e;
                ps[wave][(quad * 4 + r) * KROW + cb * 16 + l16] = f2bf(e);
            }
        }
#pragma unroll
        for (int r = 0; r < 4; r++) {
            float s = rsum[r];
#pragma unroll
            for (int off = 1; off < 16; off <<= 1) s += __shfl_xor(s, off);
            l_i[r] += s;
#pragma unroll
            for (int nb = 0; nb < 4; nb++) o_acc[nb][r] *= alpha[r];
        }

        asm volatile("s_waitcnt lgkmcnt(0)" ::: "memory");

        // ---- PV: P[16 x 64] @ V[64 x 64] ----
        const bf16x8 ap0 = *(const bf16x8*)&ps[wave][l16 * KROW + quad * 8];
        const bf16x8 ap1 = *(const bf16x8*)&ps[wave][l16 * KROW + 32 + quad * 8];
#pragma unroll
        for (int nb = 0; nb < 4; nb++) {
            const bf16x8 bv0 = *(const bf16x8*)&vs[(nb * 16 + l16) * KROW + quad * 8];
            const bf16x8 bv1 = *(const bf16x8*)&vs[(nb * 16 + l16) * KROW + 32 + quad * 8];
            o_acc[nb] = __builtin_amdgcn_mfma_f32_16x16x32_bf16(ap0, bv0, o_acc[nb], 0, 0, 0);
            o_acc[nb] = __builtin_amdgcn_mfma_f32_16x16x32_bf16(ap1, bv1, o_acc[nb], 0, 0, 0);
        }
    }

    // ---- epilogue: LDS transpose then coalesced store to abuf[o][b*t] ----
    __syncthreads();
    float* otw = ((float*)qs) + wave * 1088;    // 64 ch x 17 (padded)
#pragma unroll
    for (int nb = 0; nb < 4; nb++) {
        const int ch = nb * 16 + l16;
#pragma unroll
        for (int r = 0; r < 4; r++)
            otw[ch * 17 + quad * 4 + r] = o_acc[nb][r] / l_i[r];
    }
    asm volatile("s_waitcnt lgkmcnt(0)" ::: "memory");
    const int tq = qt0 + wave * 16;
#pragma unroll
    for (int i = 0; i < 16; i++) {
        const int ch = i * 4 + quad;
        abuf[(size_t)(h * 64 + ch) * BT_ + (size_t)b * T_ + tq + l16] = otw[ch * 17 + l16];
    }
}

// ---------------- Launch ----------------
extern "C" void kernel_launch(void* const* d_in, const int* in_sizes, int n_in,
                              void* d_out, int out_size, void* d_ws, size_t ws_size,
                              hipStream_t stream) {
    const float* x     = (const float*)d_in[0];
    const float* cin   = (const float*)d_in[1];
    const float* gamma = (const float*)d_in[2];
    const float* beta  = (const float*)d_in[3];
    const float* w_qkv = (const float*)d_in[4];
    const float* b_qkv = (const float*)d_in[5];
    const float* w_c   = (const float*)d_in[6];
    const float* b_c   = (const float*)d_in[7];
    const float* w_p   = (const float*)d_in[8];
    const float* b_p   = (const float*)d_in[9];
    float* out = (float*)d_out;

    float* ws    = (float*)d_ws;
    float* stats = ws;                       // 1,024 f
    float* xn    = ws + 1024;                // 8,388,608 f (reused as attention out)
    float* qkv   = xn + 8388608;             // 25,165,824 f
    float* ckv   = qkv + 25165824;           // 1,261,568 f
    unsigned short* qb2 = (unsigned short*)(ckv + 1261568);   // 8,388,608 us
    unsigned short* kb2 = qb2 + 8388608;                      // 9,437,184 us
    unsigned short* vb2 = (unsigned short*)qkv;               // overlays qkv Q region
    // total ~167 MB

    gn_stats_k<<<dim3(B_ * G_), 256, 0, stream>>>(x, stats);
    gn_apply_k<<<dim3((B_ * C_ * T_) / 4 / 256), 256, 0, stream>>>(x, stats, gamma, beta, xn);
    // qkv = w_qkv(1536x512) @ xn(512x16384)
    gemm_k<<<dim3(128, 12, 1), 256, 0, stream>>>(w_qkv, xn, qkv, b_qkv, nullptr,
                                                 1536, BT_, C_, BT_, BT_, 0, 0);
    // ckv = w_c(1024x768) @ c(768x77), batched over b
    gemm_k<<<dim3(1, 8, B_), 256, 0, stream>>>(w_c, cin, ckv, b_c, nullptr,
                                               1024, L_, CD_, L_, BL_,
                                               (long long)CD_ * L_, L_);
    // pack Q,K (reads qkv q/k regions) then V (writes over qkv q region)
    pack_qk_k<<<dim3(SPAD / 64, B_ * H_, 2), 256, 0, stream>>>(qkv, ckv, qb2, kb2);
    pack_v_k<<<dim3(SPAD / 64, B_ * H_), 256, 0, stream>>>(qkv, ckv, vb2);
    // flash attention -> abuf (= xn)
    flash_k<<<dim3(T_ / 64, B_ * H_), 256, 0, stream>>>(qb2, kb2, vb2, xn);
    // out = w_p(512x512) @ a(512x1024) + b_p + x, batched over b
    gemm_k<<<dim3(8, 4, B_), 256, 0, stream>>>(w_p, xn, out, b_p, x,
                                               C_, T_, C_, BT_, T_,
                                               (long long)T_, (long long)C_ * T_);
}

// Round 3
// 487.256 us; speedup vs baseline: 42.2978x; 1.8406x over previous
//
#include <hip/hip_runtime.h>

// Problem constants
#define B_   16
#define C_   512
#define T_   1024
#define H_   8
#define D_   64
#define G_   32
#define L_   77
#define S_   1101          // T + L
#define SPAD 1152          // padded S (multiple of 64)
#define CD_  768
#define BT_  (B_*T_)       // 16384
#define BL_  (B_*L_)       // 1232
#define KROW 72            // flash LDS row stride in bf16 elems (64 + 8 pad)

typedef __bf16 bf16x8 __attribute__((ext_vector_type(8)));
typedef float  f32x4  __attribute__((ext_vector_type(4)));

static __device__ __forceinline__ unsigned short f2bf(float f) {
    unsigned int u = __float_as_uint(f);
    u = (u + 0x7fffu + ((u >> 16) & 1u)) >> 16;
    return (unsigned short)u;
}

static __device__ __forceinline__ void gload_lds16(const unsigned short* g,
                                                   unsigned short* l) {
    __builtin_amdgcn_global_load_lds(
        (const __attribute__((address_space(1))) unsigned int*)g,
        (__attribute__((address_space(3))) unsigned int*)l, 16, 0, 0);
}

// ---------------- GroupNorm statistics ----------------
__global__ __launch_bounds__(256) void gn_stats_k(const float* __restrict__ x,
                                                  float* __restrict__ stats) {
    const int bg = blockIdx.x;
    const float* p = x + (size_t)bg * 16384;
    const int tid = threadIdx.x;
    float s = 0.f, s2 = 0.f;
    for (int i = tid; i < 16384; i += 256) {
        float v = p[i];
        s += v; s2 += v * v;
    }
    __shared__ float rs[256], rs2[256];
    rs[tid] = s; rs2[tid] = s2;
    __syncthreads();
    for (int off = 128; off > 0; off >>= 1) {
        if (tid < off) { rs[tid] += rs[tid + off]; rs2[tid] += rs2[tid + off]; }
        __syncthreads();
    }
    if (tid == 0) {
        float mean = rs[0] * (1.0f / 16384.0f);
        float var  = rs2[0] * (1.0f / 16384.0f) - mean * mean;
        stats[2 * bg]     = mean;
        stats[2 * bg + 1] = rsqrtf(var + 1e-5f);
    }
}

// -------- GroupNorm apply + transpose + bf16 pack into GEMM-B layout --------
// Output xnT packed: chunk(n,k) at ((nt*8 + kt)*8 + k8)*1024 + (n%128)*8, n=b*1024+t, k=c.
__global__ __launch_bounds__(256) void gn_apply_t(const float* __restrict__ x,
                                                  const float* __restrict__ stats,
                                                  const float* __restrict__ gamma,
                                                  const float* __restrict__ beta,
                                                  unsigned short* __restrict__ xnT) {
    const int t0 = blockIdx.x * 64, kt = blockIdx.y, b = blockIdx.z;
    const int c0 = kt * 64;
    const int tid = threadIdx.x;
    __shared__ float st[64][66];   // [t][c]
#pragma unroll
    for (int it = 0; it < 4; it++) {
        const int fid = it * 256 + tid;
        const int ci = fid >> 4, t4 = (fid & 15) * 4;
        const int c = c0 + ci;
        const float4 xv = *(const float4*)&x[((size_t)(b * C_ + c) << 10) + t0 + t4];
        const int bg = b * G_ + (c >> 4);
        const float mean = stats[2 * bg], istd = stats[2 * bg + 1];
        const float gs = gamma[c] * istd, gb = beta[c] - mean * gs;
        st[t4 + 0][ci] = xv.x * gs + gb;
        st[t4 + 1][ci] = xv.y * gs + gb;
        st[t4 + 2][ci] = xv.z * gs + gb;
        st[t4 + 3][ci] = xv.w * gs + gb;
    }
    __syncthreads();
#pragma unroll
    for (int it = 0; it < 2; it++) {
        const int cid = it * 256 + tid;
        const int k8 = cid >> 6, tl = cid & 63;
        const int n = (b << 10) + t0 + tl;
        const int nt = n >> 7, nm = n & 127;
        unsigned short tmp[8];
        const float* src = &st[tl][k8 * 8];
#pragma unroll
        for (int q = 0; q < 8; q++) tmp[q] = f2bf(src[q]);
        *(uint4*)&xnT[(((size_t)nt * 8 + kt) * 8 + k8) * 1024 + (size_t)nm * 8] = *(uint4*)tmp;
    }
}

// ---------- Weight converter: fp32 -> bf16 packed A layout ----------
// slot = ((mt*8 + kt)*8 + k8)*128 + ml  maps to  W[mt*128+ml][kt*64 + k8*8 .. +8)
__global__ __launch_bounds__(256) void conv_w_k(const float* __restrict__ w_qkv,
                                                const float* __restrict__ w_p,
                                                unsigned short* __restrict__ wqkv_pk,
                                                unsigned short* __restrict__ wp_pk) {
    const int cid = blockIdx.x * 256 + threadIdx.x;   // 131072 total
    const float* src;
    unsigned short* dst;
    if (cid < 98304) {   // w_qkv 1536x512
        const int ml = cid & 127, k8 = (cid >> 7) & 7, kt = (cid >> 10) & 7, mt = cid >> 13;
        src = w_qkv + (size_t)(mt * 128 + ml) * 512 + kt * 64 + k8 * 8;
        dst = wqkv_pk + (size_t)cid * 8;
    } else {             // w_p 512x512
        const int c2 = cid - 98304;
        const int ml = c2 & 127, k8 = (c2 >> 7) & 7, kt = (c2 >> 10) & 7, mt = c2 >> 13;
        src = w_p + (size_t)(mt * 128 + ml) * 512 + kt * 64 + k8 * 8;
        dst = wp_pk + (size_t)c2 * 8;
    }
    const float4 v0 = *(const float4*)src, v1 = *(const float4*)(src + 4);
    unsigned short tmp[8];
    tmp[0] = f2bf(v0.x); tmp[1] = f2bf(v0.y); tmp[2] = f2bf(v0.z); tmp[3] = f2bf(v0.w);
    tmp[4] = f2bf(v1.x); tmp[5] = f2bf(v1.y); tmp[6] = f2bf(v1.z); tmp[7] = f2bf(v1.w);
    *(uint4*)dst = *(uint4*)tmp;
}

// ---------------- Generic tiled SGEMM (fp32) — cross kv only ----------------
__global__ __launch_bounds__(256) void gemm_k(const float* __restrict__ A,
                                              const float* __restrict__ Bm,
                                              float* __restrict__ Cm,
                                              const float* __restrict__ bias,
                                              int M, int N, int K, int ldb, int ldc,
                                              long long strideB, long long strideC) {
    __shared__ float As[8][128];
    __shared__ float Bs[8][128];
    const int tid = threadIdx.x;
    const int m0 = blockIdx.y * 128, n0 = blockIdx.x * 128;
    const float* Bb = Bm + (long long)blockIdx.z * strideB;
    float* Cb = Cm + (long long)blockIdx.z * strideC;

    const int tx = tid & 15, ty = tid >> 4;
    const int arow = tid >> 1, acol = (tid & 1) * 4;
    const int brow = tid >> 5, bcol = (tid & 31) * 4;

    float acc[8][8];
#pragma unroll
    for (int i = 0; i < 8; i++)
#pragma unroll
        for (int j = 0; j < 8; j++) acc[i][j] = 0.f;

    for (int k0 = 0; k0 < K; k0 += 8) {
        float a0 = 0, a1 = 0, a2 = 0, a3 = 0;
        if (m0 + arow < M) {
            const float* ap = A + (size_t)(m0 + arow) * K + k0 + acol;
            a0 = ap[0]; a1 = ap[1]; a2 = ap[2]; a3 = ap[3];
        }
        float b0 = 0, b1 = 0, b2 = 0, b3 = 0;
        {
            const float* bp = Bb + (size_t)(k0 + brow) * ldb + n0 + bcol;
            const int nrem = N - (n0 + bcol);
            if (nrem >= 4) { b0 = bp[0]; b1 = bp[1]; b2 = bp[2]; b3 = bp[3]; }
            else {
                if (nrem > 0) b0 = bp[0];
                if (nrem > 1) b1 = bp[1];
                if (nrem > 2) b2 = bp[2];
            }
        }
        __syncthreads();
        As[acol + 0][arow] = a0; As[acol + 1][arow] = a1;
        As[acol + 2][arow] = a2; As[acol + 3][arow] = a3;
        *(float4*)&Bs[brow][bcol] = make_float4(b0, b1, b2, b3);
        __syncthreads();
#pragma unroll
        for (int kk = 0; kk < 8; kk++) {
            float4 av0 = *(const float4*)&As[kk][ty * 8];
            float4 av1 = *(const float4*)&As[kk][ty * 8 + 4];
            float4 bv0 = *(const float4*)&Bs[kk][tx * 8];
            float4 bv1 = *(const float4*)&Bs[kk][tx * 8 + 4];
            float am[8] = {av0.x, av0.y, av0.z, av0.w, av1.x, av1.y, av1.z, av1.w};
            float bn[8] = {bv0.x, bv0.y, bv0.z, bv0.w, bv1.x, bv1.y, bv1.z, bv1.w};
#pragma unroll
            for (int i = 0; i < 8; i++)
#pragma unroll
                for (int j = 0; j < 8; j++) acc[i][j] += am[i] * bn[j];
        }
    }
#pragma unroll
    for (int i = 0; i < 8; i++) {
        const int cm = m0 + ty * 8 + i;
        if (cm < M) {
            const float bv = bias ? bias[cm] : 0.f;
#pragma unroll
            for (int j = 0; j < 8; j++) {
                const int cn = n0 + tx * 8 + j;
                if (cn < N) Cb[(size_t)cm * ldc + cn] = acc[i][j] + bv;
            }
        }
    }
}

// ---------- Pack cross K/V (tokens 1024..1151, incl. zero pad) ----------
__global__ __launch_bounds__(256) void pack_cross_k(const float* __restrict__ ckv,
                                                    unsigned short* __restrict__ kb,
                                                    unsigned short* __restrict__ vb) {
    const int bh = blockIdx.x;
    const int b = bh >> 3, h = bh & 7;
    const int tid = threadIdx.x;
    // V: rows ch, cols s=1024+j  (coalesced both sides)
#pragma unroll
    for (int it = 0; it < 32; it++) {
        const int idx = it * 256 + tid;
        const int ch = idx >> 7, j = idx & 127;
        const float v = (j < L_) ? ckv[(size_t)(512 + h * 64 + ch) * BL_ + b * L_ + j] : 0.f;
        vb[((size_t)bh * 64 + ch) * SPAD + 1024 + j] = f2bf(v);
    }
    // K: rows tok=1024+j, cols ch (writes coalesced; reads strided but tiny)
#pragma unroll
    for (int it = 0; it < 32; it++) {
        const int idx = it * 256 + tid;
        const int j = idx >> 6, ch = idx & 63;
        const float v = (j < L_) ? ckv[(size_t)(h * 64 + ch) * BL_ + b * L_ + j] : 0.f;
        kb[((size_t)bh * SPAD + 1024 + j) * 64 + ch] = f2bf(v);
    }
}

// ---------------- MFMA bf16 GEMM, 128x128 tile, BK=64 ----------------
// C[m][n] = sum_k A[m][k]*B[n][k] over packed operands. K=512 fixed.
// MODE 0: qkv -> writes Q/K/V bf16 in flash layouts (+bias).
// MODE 1: proj -> writes fp32 out[b][m][t] = C + bias + resid.
template<int MODE>
__global__ __launch_bounds__(256) void mgemm_k(const unsigned short* __restrict__ Apk,
                                               const unsigned short* __restrict__ Bpk,
                                               const float* __restrict__ bias,
                                               const float* __restrict__ resid,
                                               unsigned short* __restrict__ qb,
                                               unsigned short* __restrict__ kb,
                                               unsigned short* __restrict__ vb,
                                               float* __restrict__ outp) {
    __shared__ unsigned short lds[16896];   // staging: A[0,8192) B[8192,16384); epi: 4x4224
    const int tid = threadIdx.x, wave = tid >> 6, lane = tid & 63;
    const int quad = lane >> 4, l16 = lane & 15;
    const int nt = blockIdx.x, mt = blockIdx.y;
    const int mw = (wave & 1) * 64, nw = (wave >> 1) * 64;

    f32x4 acc[4][4];
#pragma unroll
    for (int i = 0; i < 4; i++)
#pragma unroll
        for (int j = 0; j < 4; j++) acc[i][j] = (f32x4){0.f, 0.f, 0.f, 0.f};

    const unsigned short* Ab = Apk + (size_t)mt * 8 * 8192;
    const unsigned short* Bb = Bpk + (size_t)nt * 8 * 8192;

    for (int kt = 0; kt < 8; kt++) {
        const unsigned short* as = Ab + kt * 8192 + wave * 2048 + lane * 8;
        const unsigned short* bs = Bb + kt * 8192 + wave * 2048 + lane * 8;
        unsigned short* la = lds + wave * 2048;
        unsigned short* lb = lds + 8192 + wave * 2048;
#pragma unroll
        for (int j = 0; j < 4; j++) {
            gload_lds16(as + j * 512, la + j * 512);
            gload_lds16(bs + j * 512, lb + j * 512);
        }
        __syncthreads();
#pragma unroll
        for (int kh = 0; kh < 2; kh++) {
            const int k8 = kh * 4 + quad;
            bf16x8 af[4], bf[4];
#pragma unroll
            for (int i = 0; i < 4; i++) {
                af[i] = *(const bf16x8*)&lds[(size_t)(k8 * 128 + mw + i * 16 + l16) * 8];
                bf[i] = *(const bf16x8*)&lds[8192 + (size_t)(k8 * 128 + nw + i * 16 + l16) * 8];
            }
#pragma unroll
            for (int mi = 0; mi < 4; mi++)
#pragma unroll
                for (int ni = 0; ni < 4; ni++)
                    acc[mi][ni] = __builtin_amdgcn_mfma_f32_16x16x32_bf16(
                        af[mi], bf[ni], acc[mi][ni], 0, 0, 0);
        }
        __syncthreads();
    }

    const int gm0 = mt * 128 + mw;
    const int gn0 = nt * 128 + nw;

    if (MODE == 0) {
        const int region = gm0 >> 9;          // 0=Q 1=K 2=V (block-uniform)
        const int o0 = gm0 & 511;
        const int h = o0 >> 6;
        const int b = gn0 >> 10, t0 = gn0 & 1023;
        const int bh = b * 8 + h;
        unsigned short* wlds = lds + wave * 4224;   // 64 x 66
        if (region < 2) {
            // transposed [token][ch]
#pragma unroll
            for (int mi = 0; mi < 4; mi++)
#pragma unroll
                for (int ni = 0; ni < 4; ni++)
#pragma unroll
                    for (int r = 0; r < 4; r++) {
                        const float v = acc[mi][ni][r] + bias[gm0 + mi * 16 + quad * 4 + r];
                        wlds[(ni * 16 + l16) * 66 + mi * 16 + quad * 4 + r] = f2bf(v);
                    }
            __syncthreads();
            unsigned short* dst = (region == 0)
                ? qb + ((size_t)bh * 1024 + t0) * 64
                : kb + ((size_t)bh * SPAD + t0) * 64;
            const int ch8 = lane & 7, tb = lane >> 3;
#pragma unroll
            for (int it = 0; it < 8; it++) {
                const int tl = it * 8 + tb;
                *(uint4*)&dst[(size_t)tl * 64 + ch8 * 8] = *(const uint4*)&wlds[tl * 66 + ch8 * 8];
            }
        } else {
            // direct [ch][s]
#pragma unroll
            for (int mi = 0; mi < 4; mi++)
#pragma unroll
                for (int ni = 0; ni < 4; ni++)
#pragma unroll
                    for (int r = 0; r < 4; r++) {
                        const float v = acc[mi][ni][r] + bias[gm0 + mi * 16 + quad * 4 + r];
                        wlds[(mi * 16 + quad * 4 + r) * 66 + ni * 16 + l16] = f2bf(v);
                    }
            __syncthreads();
            const int s8 = lane & 7, cb = lane >> 3;
#pragma unroll
            for (int it = 0; it < 8; it++) {
                const int ch = it * 8 + cb;
                *(uint4*)&vb[((size_t)bh * 64 + ch) * SPAD + t0 + s8 * 8] =
                    *(const uint4*)&wlds[ch * 66 + s8 * 8];
            }
        }
    } else {
        // proj: fp32 + bias + residual, out[b][m][t]
        const int b = gn0 >> 10, t0 = gn0 & 1023;
#pragma unroll
        for (int mi = 0; mi < 4; mi++) {
#pragma unroll
            for (int r = 0; r < 4; r++) {
                const int m = gm0 + mi * 16 + quad * 4 + r;
                const float bv = bias[m];
                const size_t rowb = ((size_t)(b * C_ + m) << 10) + t0;
#pragma unroll
                for (int ni = 0; ni < 4; ni++) {
                    const size_t a = rowb + ni * 16 + l16;
                    outp[a] = acc[mi][ni][r] + bv + resid[a];
                }
            }
        }
    }
}

// ---------------- Flash attention, MFMA bf16 16x16x32 ----------------
__global__ __launch_bounds__(256) void flash_k(const unsigned short* __restrict__ qb,
                                               const unsigned short* __restrict__ kb,
                                               const unsigned short* __restrict__ vb,
                                               unsigned short* __restrict__ aT) {
    __shared__ __align__(16) unsigned short qs[64 * KROW];
    __shared__ __align__(16) unsigned short ks[64 * KROW];
    __shared__ __align__(16) unsigned short vs[64 * KROW];
    __shared__ __align__(16) unsigned short ps[4][16 * KROW];

    const int tid  = threadIdx.x;
    const int wave = tid >> 6, lane = tid & 63;
    const int quad = lane >> 4, l16 = lane & 15;
    const int bh  = blockIdx.y;
    const int b = bh >> 3, h = bh & 7;
    const int qt0 = blockIdx.x * 64;

    {
        const int row = tid >> 2, col = (tid & 3) * 16;
        const unsigned short* src = qb + ((size_t)bh * 1024 + qt0) * 64;
        *(uint4*)&qs[row * KROW + col]     = *(const uint4*)&src[row * 64 + col];
        *(uint4*)&qs[row * KROW + col + 8] = *(const uint4*)&src[row * 64 + col + 8];
    }
    __syncthreads();

    const int qrow = wave * 16 + l16;
    const bf16x8 aq0 = *(const bf16x8*)&qs[qrow * KROW + quad * 8];
    const bf16x8 aq1 = *(const bf16x8*)&qs[qrow * KROW + 32 + quad * 8];

    float m_i[4], l_i[4];
    f32x4 o_acc[4];
#pragma unroll
    for (int r = 0; r < 4; r++) { m_i[r] = -1e30f; l_i[r] = 0.f; }
#pragma unroll
    for (int nb = 0; nb < 4; nb++) o_acc[nb] = (f32x4){0.f, 0.f, 0.f, 0.f};

    for (int s0 = 0; s0 < SPAD; s0 += 64) {
        __syncthreads();
        {
            const int row = tid >> 2, col = (tid & 3) * 16;
            const unsigned short* ksrc = kb + ((size_t)bh * SPAD + s0 + row) * 64;
            *(uint4*)&ks[row * KROW + col]     = *(const uint4*)&ksrc[col];
            *(uint4*)&ks[row * KROW + col + 8] = *(const uint4*)&ksrc[col + 8];
            const unsigned short* vsrc = vb + ((size_t)bh * 64 + row) * SPAD + s0;
            *(uint4*)&vs[row * KROW + col]     = *(const uint4*)&vsrc[col];
            *(uint4*)&vs[row * KROW + col + 8] = *(const uint4*)&vsrc[col + 8];
        }
        __syncthreads();

        f32x4 sacc[4];
#pragma unroll
        for (int cb = 0; cb < 4; cb++) {
            const bf16x8 bk0 = *(const bf16x8*)&ks[(cb * 16 + l16) * KROW + quad * 8];
            const bf16x8 bk1 = *(const bf16x8*)&ks[(cb * 16 + l16) * KROW + 32 + quad * 8];
            f32x4 z = (f32x4){0.f, 0.f, 0.f, 0.f};
            z = __builtin_amdgcn_mfma_f32_16x16x32_bf16(aq0, bk0, z, 0, 0, 0);
            z = __builtin_amdgcn_mfma_f32_16x16x32_bf16(aq1, bk1, z, 0, 0, 0);
            sacc[cb] = z;
        }

        float p[4][4];
#pragma unroll
        for (int cb = 0; cb < 4; cb++) {
            const bool valid = (s0 + cb * 16 + l16) < S_;
#pragma unroll
            for (int r = 0; r < 4; r++)
                p[cb][r] = valid ? sacc[cb][r] * 0.125f : -1e30f;
        }

        float rm[4], alpha[4];
#pragma unroll
        for (int r = 0; r < 4; r++) {
            float m = fmaxf(fmaxf(p[0][r], p[1][r]), fmaxf(p[2][r], p[3][r]));
#pragma unroll
            for (int off = 1; off < 16; off <<= 1) m = fmaxf(m, __shfl_xor(m, off));
            rm[r] = m;
        }
#pragma unroll
        for (int r = 0; r < 4; r++) {
            const float mo = m_i[r];
            const float mn = fmaxf(mo, rm[r]);
            m_i[r] = mn;
            alpha[r] = __expf(mo - mn);
            l_i[r] *= alpha[r];
        }

        float rsum[4] = {0.f, 0.f, 0.f, 0.f};
#pragma unroll
        for (int cb = 0; cb < 4; cb++) {
#pragma unroll
            for (int r = 0; r < 4; r++) {
                const float e = __expf(p[cb][r] - m_i[r]);
                rsum[r] += e;
                ps[wave][(quad * 4 + r) * KROW + cb * 16 + l16] = f2bf(e);
            }
        }
#pragma unroll
        for (int r = 0; r < 4; r++) {
            float s = rsum[r];
#pragma unroll
            for (int off = 1; off < 16; off <<= 1) s += __shfl_xor(s, off);
            l_i[r] += s;
#pragma unroll
            for (int nb = 0; nb < 4; nb++) o_acc[nb][r] *= alpha[r];
        }

        asm volatile("s_waitcnt lgkmcnt(0)" ::: "memory");

        const bf16x8 ap0 = *(const bf16x8*)&ps[wave][l16 * KROW + quad * 8];
        const bf16x8 ap1 = *(const bf16x8*)&ps[wave][l16 * KROW + 32 + quad * 8];
#pragma unroll
        for (int nb = 0; nb < 4; nb++) {
            const bf16x8 bv0 = *(const bf16x8*)&vs[(nb * 16 + l16) * KROW + quad * 8];
            const bf16x8 bv1 = *(const bf16x8*)&vs[(nb * 16 + l16) * KROW + 32 + quad * 8];
            o_acc[nb] = __builtin_amdgcn_mfma_f32_16x16x32_bf16(ap0, bv0, o_acc[nb], 0, 0, 0);
            o_acc[nb] = __builtin_amdgcn_mfma_f32_16x16x32_bf16(ap1, bv1, o_acc[nb], 0, 0, 0);
        }
    }

    // ---- epilogue: bf16, packed-B layout for proj GEMM (kt = h) ----
    __syncthreads();
    unsigned short* otw = &ps[wave][0];     // [t 16][KROW]
#pragma unroll
    for (int nb = 0; nb < 4; nb++) {
        const int ch = nb * 16 + l16;
#pragma unroll
        for (int r = 0; r < 4; r++)
            otw[(quad * 4 + r) * KROW + ch] = f2bf(o_acc[nb][r] / l_i[r]);
    }
    asm volatile("s_waitcnt lgkmcnt(0)" ::: "memory");
    const int k8 = lane >> 3;
#pragma unroll
    for (int it = 0; it < 2; it++) {
        const int tl = (lane & 7) + it * 8;
        const int n = (b << 10) + qt0 + wave * 16 + tl;
        const int ntb = n >> 7, nm = n & 127;
        *(uint4*)&aT[(((size_t)ntb * 8 + h) * 8 + k8) * 1024 + (size_t)nm * 8] =
            *(const uint4*)&otw[tl * KROW + k8 * 8];
    }
}

// ---------------- Launch ----------------
extern "C" void kernel_launch(void* const* d_in, const int* in_sizes, int n_in,
                              void* d_out, int out_size, void* d_ws, size_t ws_size,
                              hipStream_t stream) {
    const float* x     = (const float*)d_in[0];
    const float* cin   = (const float*)d_in[1];
    const float* gamma = (const float*)d_in[2];
    const float* beta  = (const float*)d_in[3];
    const float* w_qkv = (const float*)d_in[4];
    const float* b_qkv = (const float*)d_in[5];
    const float* w_c   = (const float*)d_in[6];
    const float* b_c   = (const float*)d_in[7];
    const float* w_p   = (const float*)d_in[8];
    const float* b_p   = (const float*)d_in[9];
    float* out = (float*)d_out;

    float* ws    = (float*)d_ws;
    float* stats = ws;                                  // 1,024 f
    float* ckv   = ws + 1024;                           // 1,261,568 f
    unsigned short* xnT     = (unsigned short*)(ckv + 1261568);  // 8,388,608 us
    unsigned short* wqkv_pk = xnT + 8388608;            // 786,432 us
    unsigned short* wp_pk   = wqkv_pk + 786432;         // 262,144 us
    unsigned short* qb      = wp_pk + 262144;           // 8,388,608 us
    unsigned short* kb      = qb + 8388608;             // 9,437,184 us
    unsigned short* vb      = kb + 9437184;             // 9,437,184 us
    unsigned short* aT      = vb + 9437184;             // 8,388,608 us
    // total ~95 MB

    gn_stats_k<<<dim3(B_ * G_), 256, 0, stream>>>(x, stats);
    gn_apply_t<<<dim3(16, 8, 16), 256, 0, stream>>>(x, stats, gamma, beta, xnT);
    conv_w_k<<<dim3(512), 256, 0, stream>>>(w_qkv, w_p, wqkv_pk, wp_pk);
    // cross kv (fp32): ckv[o][b*77+l], o in [0,1024)
    gemm_k<<<dim3(1, 8, B_), 256, 0, stream>>>(w_c, cin, ckv, b_c,
                                               1024, L_, CD_, L_, BL_,
                                               (long long)CD_ * L_, L_);
    pack_cross_k<<<dim3(B_ * H_), 256, 0, stream>>>(ckv, kb, vb);
    // qkv MFMA GEMM: writes qb/kb/vb directly
    mgemm_k<0><<<dim3(128, 12), 256, 0, stream>>>(wqkv_pk, xnT, b_qkv, nullptr,
                                                  qb, kb, vb, nullptr);
    // flash attention -> aT (packed B layout)
    flash_k<<<dim3(T_ / 64, B_ * H_), 256, 0, stream>>>(qb, kb, vb, aT);
    // proj MFMA GEMM + bias + residual -> out
    mgemm_k<1><<<dim3(128, 4), 256, 0, stream>>>(wp_pk, aT, b_p, x,
                                                 nullptr, nullptr, nullptr, out);
}

// Round 4
// 324.769 us; speedup vs baseline: 63.4601x; 1.5003x over previous
//
#include <hip/hip_runtime.h>

// Problem constants
#define B_   16
#define C_   512
#define T_   1024
#define H_   8
#define D_   64
#define G_   32
#define L_   77
#define S_   1101          // T + L
#define SPAD 1152          // padded S (multiple of 64)
#define NPAD 51            // SPAD - S_ : zero-pad tokens, each adds exp2(0)=1 to l
#define CD_  768
#define BT_  (B_*T_)       // 16384
#define BL_  (B_*L_)       // 1232
#define KROW 72            // flash LDS row stride (bf16 elems) for Q/K/V tiles
#define QSC  0.18033688011112042f   // 0.125 * log2(e): folded into Q

typedef __bf16 bf16x8 __attribute__((ext_vector_type(8)));
typedef float  f32x4  __attribute__((ext_vector_type(4)));

static __device__ __forceinline__ unsigned short f2bf(float f) {
    unsigned int u = __float_as_uint(f);
    u = (u + 0x7fffu + ((u >> 16) & 1u)) >> 16;
    return (unsigned short)u;
}

static __device__ __forceinline__ void gload_lds16(const unsigned short* g,
                                                   unsigned short* l) {
    __builtin_amdgcn_global_load_lds(
        (const __attribute__((address_space(1))) unsigned int*)g,
        (__attribute__((address_space(3))) unsigned int*)l, 16, 0, 0);
}

// -------- prep: GroupNorm stats (blocks 0..511) + weight bf16 packing --------
__global__ __launch_bounds__(256) void prep_k(const float* __restrict__ x,
                                              float* __restrict__ stats,
                                              const float* __restrict__ w_qkv,
                                              const float* __restrict__ w_p,
                                              const float* __restrict__ w_c,
                                              unsigned short* __restrict__ wqkv_pk,
                                              unsigned short* __restrict__ wp_pk,
                                              unsigned short* __restrict__ wc_pk) {
    const int tid = threadIdx.x;
    if (blockIdx.x < 512) {
        const int bg = blockIdx.x;
        const float* p = x + (size_t)bg * 16384;
        float s = 0.f, s2 = 0.f;
        for (int i = tid; i < 16384; i += 256) {
            float v = p[i];
            s += v; s2 += v * v;
        }
        __shared__ float rs[256], rs2[256];
        rs[tid] = s; rs2[tid] = s2;
        __syncthreads();
        for (int off = 128; off > 0; off >>= 1) {
            if (tid < off) { rs[tid] += rs[tid + off]; rs2[tid] += rs2[tid + off]; }
            __syncthreads();
        }
        if (tid == 0) {
            float mean = rs[0] * (1.0f / 16384.0f);
            float var  = rs2[0] * (1.0f / 16384.0f) - mean * mean;
            stats[2 * bg]     = mean;
            stats[2 * bg + 1] = rsqrtf(var + 1e-5f);
        }
        return;
    }
    // weight packing: 229376 chunks of 8
    const int cid = (blockIdx.x - 512) * 256 + tid;
    const float* src;
    unsigned short* dst;
    if (cid < 98304) {                 // w_qkv 1536x512, KT=8
        const int ml = cid & 127, k8 = (cid >> 7) & 7, kt = (cid >> 10) & 7, mt = cid >> 13;
        src = w_qkv + (size_t)(mt * 128 + ml) * 512 + kt * 64 + k8 * 8;
        dst = wqkv_pk + (size_t)cid * 8;
    } else if (cid < 131072) {         // w_p 512x512, KT=8
        const int c2 = cid - 98304;
        const int ml = c2 & 127, k8 = (c2 >> 7) & 7, kt = (c2 >> 10) & 7, mt = c2 >> 13;
        src = w_p + (size_t)(mt * 128 + ml) * 512 + kt * 64 + k8 * 8;
        dst = wp_pk + (size_t)c2 * 8;
    } else {                           // w_c 1024x768, KT=12
        const int c3 = cid - 131072;
        const int ml = c3 & 127, k8 = (c3 >> 7) & 7;
        const int ktmt = c3 >> 10;
        const int kt = ktmt % 12, mt = ktmt / 12;
        src = w_c + (size_t)(mt * 128 + ml) * 768 + kt * 64 + k8 * 8;
        dst = wc_pk + (size_t)c3 * 8;
    }
    const float4 v0 = *(const float4*)src, v1 = *(const float4*)(src + 4);
    unsigned short tmp[8];
    tmp[0] = f2bf(v0.x); tmp[1] = f2bf(v0.y); tmp[2] = f2bf(v0.z); tmp[3] = f2bf(v0.w);
    tmp[4] = f2bf(v1.x); tmp[5] = f2bf(v1.y); tmp[6] = f2bf(v1.z); tmp[7] = f2bf(v1.w);
    *(uint4*)dst = *(uint4*)tmp;
}

// -------- GroupNorm apply + transpose + bf16 pack into GEMM-B layout --------
__global__ __launch_bounds__(256) void gn_apply_t(const float* __restrict__ x,
                                                  const float* __restrict__ stats,
                                                  const float* __restrict__ gamma,
                                                  const float* __restrict__ beta,
                                                  unsigned short* __restrict__ xnT) {
    const int t0 = blockIdx.x * 64, kt = blockIdx.y, b = blockIdx.z;
    const int c0 = kt * 64;
    const int tid = threadIdx.x;
    __shared__ float st[64][66];   // [t][c]
#pragma unroll
    for (int it = 0; it < 4; it++) {
        const int fid = it * 256 + tid;
        const int ci = fid >> 4, t4 = (fid & 15) * 4;
        const int c = c0 + ci;
        const float4 xv = *(const float4*)&x[((size_t)(b * C_ + c) << 10) + t0 + t4];
        const int bg = b * G_ + (c >> 4);
        const float mean = stats[2 * bg], istd = stats[2 * bg + 1];
        const float gs = gamma[c] * istd, gb = beta[c] - mean * gs;
        st[t4 + 0][ci] = xv.x * gs + gb;
        st[t4 + 1][ci] = xv.y * gs + gb;
        st[t4 + 2][ci] = xv.z * gs + gb;
        st[t4 + 3][ci] = xv.w * gs + gb;
    }
    __syncthreads();
#pragma unroll
    for (int it = 0; it < 2; it++) {
        const int cid = it * 256 + tid;
        const int k8 = cid >> 6, tl = cid & 63;
        const int n = (b << 10) + t0 + tl;
        const int nt = n >> 7, nm = n & 127;
        unsigned short tmp[8];
        const float* src = &st[tl][k8 * 8];
#pragma unroll
        for (int q = 0; q < 8; q++) tmp[q] = f2bf(src[q]);
        *(uint4*)&xnT[(((size_t)nt * 8 + kt) * 8 + k8) * 1024 + (size_t)nm * 8] = *(uint4*)tmp;
    }
}

// -------- pack cross input c [b][768][77] -> B layout per batch (KT=12) --------
__global__ __launch_bounds__(256) void pack_c_k(const float* __restrict__ c,
                                                unsigned short* __restrict__ cpk) {
    const int kt = blockIdx.x, b = blockIdx.y;
#pragma unroll
    for (int it = 0; it < 4; it++) {
        const int idx = it * 256 + threadIdx.x;   // 1024 chunks per (kt,b)
        const int k8 = idx >> 7, l = idx & 127;
        unsigned short tmp[8];
        const float* src = c + ((size_t)b * CD_ + kt * 64 + k8 * 8) * L_ + l;
#pragma unroll
        for (int q = 0; q < 8; q++)
            tmp[q] = (l < L_) ? f2bf(src[(size_t)q * L_]) : (unsigned short)0;
        *(uint4*)&cpk[(size_t)b * 98304 + ((size_t)(kt * 8 + k8)) * 1024 + (size_t)l * 8] =
            *(uint4*)tmp;
    }
}

// ---------------- MFMA bf16 GEMM, 128x128 tile, BK=64 ----------------
// MODE 0: qkv (KT=8)  -> Q(scaled by QSC)/K/V bf16 in flash layouts (+bias).
// MODE 1: proj (KT=8) -> fp32 out = C + bias + resid.
// MODE 2: cross (KT=12, batched z) -> Kc/Vc into kb/vb at tokens 1024+, pad->0.
template<int MODE, int KT>
__global__ __launch_bounds__(256) void mgemm_k(const unsigned short* __restrict__ Apk,
                                               const unsigned short* __restrict__ Bpk,
                                               const float* __restrict__ bias,
                                               const float* __restrict__ resid,
                                               unsigned short* __restrict__ qb,
                                               unsigned short* __restrict__ kb,
                                               unsigned short* __restrict__ vb,
                                               float* __restrict__ outp) {
    __shared__ unsigned short lds[16896];   // staging A[0,8192) B[8192,16384); epi 4x4224
    const int tid = threadIdx.x, wave = tid >> 6, lane = tid & 63;
    const int quad = lane >> 4, l16 = lane & 15;
    const int nt = blockIdx.x, mt = blockIdx.y;
    const int mw = (wave & 1) * 64, nw = (wave >> 1) * 64;

    f32x4 acc[4][4];
#pragma unroll
    for (int i = 0; i < 4; i++)
#pragma unroll
        for (int j = 0; j < 4; j++) acc[i][j] = (f32x4){0.f, 0.f, 0.f, 0.f};

    const unsigned short* Ab = Apk + (size_t)mt * KT * 8192;
    const unsigned short* Bb = Bpk + ((MODE == 2) ? (size_t)blockIdx.z * KT * 8192 : 0)
                                   + (size_t)nt * KT * 8192;

    for (int kt = 0; kt < KT; kt++) {
        const unsigned short* as = Ab + kt * 8192 + wave * 2048 + lane * 8;
        const unsigned short* bs = Bb + kt * 8192 + wave * 2048 + lane * 8;
        unsigned short* la = lds + wave * 2048;
        unsigned short* lb = lds + 8192 + wave * 2048;
#pragma unroll
        for (int j = 0; j < 4; j++) {
            gload_lds16(as + j * 512, la + j * 512);
            gload_lds16(bs + j * 512, lb + j * 512);
        }
        __syncthreads();
#pragma unroll
        for (int kh = 0; kh < 2; kh++) {
            const int k8 = kh * 4 + quad;
            bf16x8 af[4], bfr[4];
#pragma unroll
            for (int i = 0; i < 4; i++) {
                af[i]  = *(const bf16x8*)&lds[(size_t)(k8 * 128 + mw + i * 16 + l16) * 8];
                bfr[i] = *(const bf16x8*)&lds[8192 + (size_t)(k8 * 128 + nw + i * 16 + l16) * 8];
            }
#pragma unroll
            for (int mi = 0; mi < 4; mi++)
#pragma unroll
                for (int ni = 0; ni < 4; ni++)
                    acc[mi][ni] = __builtin_amdgcn_mfma_f32_16x16x32_bf16(
                        af[mi], bfr[ni], acc[mi][ni], 0, 0, 0);
        }
        __syncthreads();
    }

    const int gm0 = mt * 128 + mw;
    const int gn0 = nt * 128 + nw;

    if (MODE == 0) {
        const int region = gm0 >> 9;          // 0=Q 1=K 2=V (wave-uniform)
        const int o0 = gm0 & 511;
        const int h = o0 >> 6;
        const int b = gn0 >> 10, t0 = gn0 & 1023;
        const int bh = b * 8 + h;
        unsigned short* wlds = lds + wave * 4224;   // 64 x 66
        if (region < 2) {
            const float sc = (region == 0) ? QSC : 1.0f;
#pragma unroll
            for (int mi = 0; mi < 4; mi++)
#pragma unroll
                for (int ni = 0; ni < 4; ni++)
#pragma unroll
                    for (int r = 0; r < 4; r++) {
                        const float v = (acc[mi][ni][r] + bias[gm0 + mi * 16 + quad * 4 + r]) * sc;
                        wlds[(ni * 16 + l16) * 66 + mi * 16 + quad * 4 + r] = f2bf(v);
                    }
            __syncthreads();
            unsigned short* dst = (region == 0)
                ? qb + ((size_t)bh * 1024 + t0) * 64
                : kb + ((size_t)bh * SPAD + t0) * 64;
            const int ch8 = lane & 7, tb = lane >> 3;
#pragma unroll
            for (int it = 0; it < 8; it++) {
                const int tl = it * 8 + tb;
                *(uint4*)&dst[(size_t)tl * 64 + ch8 * 8] = *(const uint4*)&wlds[tl * 66 + ch8 * 8];
            }
        } else {
#pragma unroll
            for (int mi = 0; mi < 4; mi++)
#pragma unroll
                for (int ni = 0; ni < 4; ni++)
#pragma unroll
                    for (int r = 0; r < 4; r++) {
                        const float v = acc[mi][ni][r] + bias[gm0 + mi * 16 + quad * 4 + r];
                        wlds[(mi * 16 + quad * 4 + r) * 66 + ni * 16 + l16] = f2bf(v);
                    }
            __syncthreads();
            const int s8 = lane & 7, cb = lane >> 3;
#pragma unroll
            for (int it = 0; it < 8; it++) {
                const int ch = it * 8 + cb;
                *(uint4*)&vb[((size_t)bh * 64 + ch) * SPAD + t0 + s8 * 8] =
                    *(const uint4*)&wlds[ch * 66 + s8 * 8];
            }
        }
    } else if (MODE == 1) {
        const int b = gn0 >> 10, t0 = gn0 & 1023;
#pragma unroll
        for (int mi = 0; mi < 4; mi++) {
#pragma unroll
            for (int r = 0; r < 4; r++) {
                const int m = gm0 + mi * 16 + quad * 4 + r;
                const float bv = bias[m];
                const size_t rowb = ((size_t)(b * C_ + m) << 10) + t0;
#pragma unroll
                for (int ni = 0; ni < 4; ni++) {
                    const size_t a = rowb + ni * 16 + l16;
                    outp[a] = acc[mi][ni][r] + bv + resid[a];
                }
            }
        }
    } else {
        // cross: gm0 in [0,1024): region 0 = Kc, 1 = Vc. tokens 1024+gn0+col, col>=77 -> 0
        const int region = gm0 >> 9;
        const int o0 = gm0 & 511;
        const int h = o0 >> 6;
        const int b = blockIdx.z;
        const int bh = b * 8 + h;
        unsigned short* wlds = lds + wave * 4224;
        if (region == 0) {
#pragma unroll
            for (int mi = 0; mi < 4; mi++)
#pragma unroll
                for (int ni = 0; ni < 4; ni++) {
                    const bool valid = (gn0 + ni * 16 + l16) < L_;
#pragma unroll
                    for (int r = 0; r < 4; r++) {
                        const float v = valid ? acc[mi][ni][r] + bias[gm0 + mi * 16 + quad * 4 + r] : 0.f;
                        wlds[(ni * 16 + l16) * 66 + mi * 16 + quad * 4 + r] = f2bf(v);
                    }
                }
            __syncthreads();
            unsigned short* dst = kb + ((size_t)bh * SPAD + 1024 + gn0) * 64;
            const int ch8 = lane & 7, tb = lane >> 3;
#pragma unroll
            for (int it = 0; it < 8; it++) {
                const int tl = it * 8 + tb;
                *(uint4*)&dst[(size_t)tl * 64 + ch8 * 8] = *(const uint4*)&wlds[tl * 66 + ch8 * 8];
            }
        } else {
#pragma unroll
            for (int mi = 0; mi < 4; mi++)
#pragma unroll
                for (int ni = 0; ni < 4; ni++) {
                    const bool valid = (gn0 + ni * 16 + l16) < L_;
#pragma unroll
                    for (int r = 0; r < 4; r++) {
                        const float v = valid ? acc[mi][ni][r] + bias[gm0 + mi * 16 + quad * 4 + r] : 0.f;
                        wlds[(mi * 16 + quad * 4 + r) * 66 + ni * 16 + l16] = f2bf(v);
                    }
                }
            __syncthreads();
            const int s8 = lane & 7, cb = lane >> 3;
#pragma unroll
            for (int it = 0; it < 8; it++) {
                const int ch = it * 8 + cb;
                *(uint4*)&vb[((size_t)bh * 64 + ch) * SPAD + 1024 + gn0 + s8 * 8] =
                    *(const uint4*)&wlds[ch * 66 + s8 * 8];
            }
        }
    }
}

// ---------------- Flash attention (no-max softmax, exp2 domain) ----------------
// Q pre-scaled by QSC; l corrected by -NPAD for the zero-pad tokens.
// Grid (bh=128, qt=16) — bh fastest for XCD K/V L2 locality.
__global__ __launch_bounds__(256) void flash_k(const unsigned short* __restrict__ qb,
                                               const unsigned short* __restrict__ kb,
                                               const unsigned short* __restrict__ vb,
                                               unsigned short* __restrict__ aT) {
    __shared__ __align__(16) unsigned short qs[64 * KROW];   // Q prologue; then per-wave P
    __shared__ __align__(16) unsigned short ks[64 * KROW];
    __shared__ __align__(16) unsigned short vs[64 * KROW];

    const int tid  = threadIdx.x;
    const int wave = tid >> 6, lane = tid & 63;
    const int quad = lane >> 4, l16 = lane & 15;
    const int bh  = blockIdx.x;
    const int b = bh >> 3, h = bh & 7;
    const int qt0 = blockIdx.y * 64;

    // stage this wave's 16 Q rows (per-wave region, no barrier needed)
    {
        const int row = tid >> 2, col = (tid & 3) * 16;
        const unsigned short* src = qb + ((size_t)bh * 1024 + qt0) * 64;
        *(uint4*)&qs[row * KROW + col]     = *(const uint4*)&src[row * 64 + col];
        *(uint4*)&qs[row * KROW + col + 8] = *(const uint4*)&src[row * 64 + col + 8];
    }
    const int qrow = wave * 16 + l16;
    const bf16x8 aq0 = *(const bf16x8*)&qs[qrow * KROW + quad * 8];
    const bf16x8 aq1 = *(const bf16x8*)&qs[qrow * KROW + 32 + quad * 8];

    // per-wave P buffer overlays this wave's Q region; row stride 64, col rotated by
    // 16*(row>>2) mod 64 -> conflict-free b16 writes, aligned b128 reads.
    unsigned short* ps = qs + wave * 16 * KROW;

    float rsum[4] = {0.f, 0.f, 0.f, 0.f};
    f32x4 o_acc[4];
#pragma unroll
    for (int nb = 0; nb < 4; nb++) o_acc[nb] = (f32x4){0.f, 0.f, 0.f, 0.f};

    for (int s0 = 0; s0 < SPAD; s0 += 64) {
        __syncthreads();
        {
            const int row = tid >> 2, col = (tid & 3) * 16;
            const unsigned short* ksrc = kb + ((size_t)bh * SPAD + s0 + row) * 64;
            *(uint4*)&ks[row * KROW + col]     = *(const uint4*)&ksrc[col];
            *(uint4*)&ks[row * KROW + col + 8] = *(const uint4*)&ksrc[col + 8];
            const unsigned short* vsrc = vb + ((size_t)bh * 64 + row) * SPAD + s0;
            *(uint4*)&vs[row * KROW + col]     = *(const uint4*)&vsrc[col];
            *(uint4*)&vs[row * KROW + col + 8] = *(const uint4*)&vsrc[col + 8];
        }
        __syncthreads();

        f32x4 sacc[4];
#pragma unroll
        for (int cb = 0; cb < 4; cb++) {
            const bf16x8 bk0 = *(const bf16x8*)&ks[(cb * 16 + l16) * KROW + quad * 8];
            const bf16x8 bk1 = *(const bf16x8*)&ks[(cb * 16 + l16) * KROW + 32 + quad * 8];
            f32x4 z = (f32x4){0.f, 0.f, 0.f, 0.f};
            z = __builtin_amdgcn_mfma_f32_16x16x32_bf16(aq0, bk0, z, 0, 0, 0);
            z = __builtin_amdgcn_mfma_f32_16x16x32_bf16(aq1, bk1, z, 0, 0, 0);
            sacc[cb] = z;
        }

        // exp2, accumulate per-lane partial l, write P (rotated columns)
#pragma unroll
        for (int cb = 0; cb < 4; cb++) {
#pragma unroll
            for (int r = 0; r < 4; r++) {
                const float e = __builtin_exp2f(sacc[cb][r]);
                rsum[r] += e;
                ps[(quad * 4 + r) * 64 + ((cb * 16 + l16 + 16 * quad) & 63)] = f2bf(e);
            }
        }
        asm volatile("s_waitcnt lgkmcnt(0)" ::: "memory");

        // PV: A-frag rows l16, logical cols quad*8..+8 -> physical rotated by 16*(l16>>2)
        const int pc0 = (quad * 8 + 16 * (l16 >> 2)) & 63;
        const int pc1 = (32 + quad * 8 + 16 * (l16 >> 2)) & 63;
        const bf16x8 ap0 = *(const bf16x8*)&ps[l16 * 64 + pc0];
        const bf16x8 ap1 = *(const bf16x8*)&ps[l16 * 64 + pc1];
#pragma unroll
        for (int nb = 0; nb < 4; nb++) {
            const bf16x8 bv0 = *(const bf16x8*)&vs[(nb * 16 + l16) * KROW + quad * 8];
            const bf16x8 bv1 = *(const bf16x8*)&vs[(nb * 16 + l16) * KROW + 32 + quad * 8];
            o_acc[nb] = __builtin_amdgcn_mfma_f32_16x16x32_bf16(ap0, bv0, o_acc[nb], 0, 0, 0);
            o_acc[nb] = __builtin_amdgcn_mfma_f32_16x16x32_bf16(ap1, bv1, o_acc[nb], 0, 0, 0);
        }
    }

    // final l: reduce over the 16 lanes of this quad, correct for zero-pad tokens
    float linv[4];
#pragma unroll
    for (int r = 0; r < 4; r++) {
        float s = rsum[r];
#pragma unroll
        for (int off = 1; off < 16; off <<= 1) s += __shfl_xor(s, off);
        linv[r] = 1.0f / (s - (float)NPAD);
    }

    // epilogue: stage O in ps (same rotation), store rows as uint4 in packed-B layout
#pragma unroll
    for (int nb = 0; nb < 4; nb++) {
#pragma unroll
        for (int r = 0; r < 4; r++)
            ps[(quad * 4 + r) * 64 + ((nb * 16 + l16 + 16 * quad) & 63)] =
                f2bf(o_acc[nb][r] * linv[r]);
    }
    asm volatile("s_waitcnt lgkmcnt(0)" ::: "memory");
    const int k8 = lane >> 3;
#pragma unroll
    for (int it = 0; it < 2; it++) {
        const int tl = (lane & 7) + it * 8;
        const int pc = (k8 * 8 + 16 * (tl >> 2)) & 63;
        const int n = (b << 10) + qt0 + wave * 16 + tl;
        const int ntb = n >> 7, nm = n & 127;
        *(uint4*)&aT[(((size_t)ntb * 8 + h) * 8 + k8) * 1024 + (size_t)nm * 8] =
            *(const uint4*)&ps[tl * 64 + pc];
    }
}

// ---------------- Launch ----------------
extern "C" void kernel_launch(void* const* d_in, const int* in_sizes, int n_in,
                              void* d_out, int out_size, void* d_ws, size_t ws_size,
                              hipStream_t stream) {
    const float* x     = (const float*)d_in[0];
    const float* cin   = (const float*)d_in[1];
    const float* gamma = (const float*)d_in[2];
    const float* beta  = (const float*)d_in[3];
    const float* w_qkv = (const float*)d_in[4];
    const float* b_qkv = (const float*)d_in[5];
    const float* w_c   = (const float*)d_in[6];
    const float* b_c   = (const float*)d_in[7];
    const float* w_p   = (const float*)d_in[8];
    const float* b_p   = (const float*)d_in[9];
    float* out = (float*)d_out;

    float* ws    = (float*)d_ws;
    float* stats = ws;                                        // 1,024 f
    unsigned short* xnT     = (unsigned short*)(ws + 1024);   // 8,388,608 us
    unsigned short* wqkv_pk = xnT + 8388608;                  // 786,432 us
    unsigned short* wp_pk   = wqkv_pk + 786432;               // 262,144 us
    unsigned short* wc_pk   = wp_pk + 262144;                 // 786,432 us
    unsigned short* cpk     = wc_pk + 786432;                 // 1,572,864 us
    unsigned short* qb      = cpk + 1572864;                  // 8,388,608 us
    unsigned short* kb      = qb + 8388608;                   // 9,437,184 us
    unsigned short* vb      = kb + 9437184;                   // 9,437,184 us
    unsigned short* aT      = vb + 9437184;                   // 8,388,608 us
    // total ~95 MB

    prep_k<<<dim3(512 + 896), 256, 0, stream>>>(x, stats, w_qkv, w_p, w_c,
                                                wqkv_pk, wp_pk, wc_pk);
    gn_apply_t<<<dim3(16, 8, 16), 256, 0, stream>>>(x, stats, gamma, beta, xnT);
    pack_c_k<<<dim3(12, 16), 256, 0, stream>>>(cin, cpk);
    // qkv MFMA GEMM -> qb (scaled) / kb / vb
    mgemm_k<0, 8><<<dim3(128, 12), 256, 0, stream>>>(wqkv_pk, xnT, b_qkv, nullptr,
                                                     qb, kb, vb, nullptr);
    // cross MFMA GEMM -> kb/vb tokens 1024.. (zero pad)
    mgemm_k<2, 12><<<dim3(1, 8, 16), 256, 0, stream>>>(wc_pk, cpk, b_c, nullptr,
                                                       nullptr, kb, vb, nullptr);
    // flash attention -> aT (packed B layout)
    flash_k<<<dim3(128, 16), 256, 0, stream>>>(qb, kb, vb, aT);
    // proj MFMA GEMM + bias + residual -> out
    mgemm_k<1, 8><<<dim3(128, 4), 256, 0, stream>>>(wp_pk, aT, b_p, x,
                                                    nullptr, nullptr, nullptr, out);
}

// Round 5
// 282.645 us; speedup vs baseline: 72.9179x; 1.1490x over previous
//
#include <hip/hip_runtime.h>

// Problem constants
#define B_   16
#define C_   512
#define T_   1024
#define H_   8
#define D_   64
#define G_   32
#define L_   77
#define S_   1101          // T + L
#define SPAD 1152          // padded S (18 tiles of 64)
#define NPAD 51            // SPAD - S_ : zero-pad tokens each add exp2(0)=1 to l
#define CD_  768
#define BT_  (B_*T_)       // 16384
#define SROW 72            // flash P/O LDS row stride (16B-aligned, conflict-spread)
#define QSC  0.18033688011112042f   // 0.125 * log2(e), folded into Q

typedef __bf16 bf16x8 __attribute__((ext_vector_type(8)));
typedef float  f32x4  __attribute__((ext_vector_type(4)));

static __device__ __forceinline__ unsigned short f2bf(float f) {
    unsigned int u = __float_as_uint(f);
    u = (u + 0x7fffu + ((u >> 16) & 1u)) >> 16;
    return (unsigned short)u;
}

// packed RNE f32x2 -> bf16x2 (single HW instruction)
static __device__ __forceinline__ unsigned int pk_bf16(float a, float b) {
    unsigned int d;
    asm("v_cvt_pk_bf16_f32 %0, %1, %2" : "=v"(d) : "v"(a), "v"(b));
    return d;
}

static __device__ __forceinline__ void gload_lds16(const unsigned short* g,
                                                   unsigned short* l) {
    __builtin_amdgcn_global_load_lds(
        (const __attribute__((address_space(1))) unsigned int*)g,
        (__attribute__((address_space(3))) unsigned int*)l, 16, 0, 0);
}

// -------- prep: GN stats (0..511) + weight packing (512..1407) + c pack (1408..1599)
__global__ __launch_bounds__(256) void prep_k(const float* __restrict__ x,
                                              float* __restrict__ stats,
                                              const float* __restrict__ w_qkv,
                                              const float* __restrict__ w_p,
                                              const float* __restrict__ w_c,
                                              const float* __restrict__ cin,
                                              unsigned short* __restrict__ wqkv_pk,
                                              unsigned short* __restrict__ wp_pk,
                                              unsigned short* __restrict__ wc_pk,
                                              unsigned short* __restrict__ cpk) {
    const int tid = threadIdx.x;
    if (blockIdx.x < 512) {
        const int bg = blockIdx.x;
        const float* p = x + (size_t)bg * 16384;
        float s = 0.f, s2 = 0.f;
        for (int i = tid; i < 16384; i += 256) {
            float v = p[i];
            s += v; s2 += v * v;
        }
        __shared__ float rs[256], rs2[256];
        rs[tid] = s; rs2[tid] = s2;
        __syncthreads();
        for (int off = 128; off > 0; off >>= 1) {
            if (tid < off) { rs[tid] += rs[tid + off]; rs2[tid] += rs2[tid + off]; }
            __syncthreads();
        }
        if (tid == 0) {
            float mean = rs[0] * (1.0f / 16384.0f);
            float var  = rs2[0] * (1.0f / 16384.0f) - mean * mean;
            stats[2 * bg]     = mean;
            stats[2 * bg + 1] = rsqrtf(var + 1e-5f);
        }
        return;
    }
    if (blockIdx.x < 1408) {
        const int cid = (blockIdx.x - 512) * 256 + tid;   // 229376 chunks
        const float* src;
        unsigned short* dst;
        if (cid < 98304) {                 // w_qkv 1536x512, KT=8
            const int ml = cid & 127, k8 = (cid >> 7) & 7, kt = (cid >> 10) & 7, mt = cid >> 13;
            src = w_qkv + (size_t)(mt * 128 + ml) * 512 + kt * 64 + k8 * 8;
            dst = wqkv_pk + (size_t)cid * 8;
        } else if (cid < 131072) {         // w_p 512x512, KT=8
            const int c2 = cid - 98304;
            const int ml = c2 & 127, k8 = (c2 >> 7) & 7, kt = (c2 >> 10) & 7, mt = c2 >> 13;
            src = w_p + (size_t)(mt * 128 + ml) * 512 + kt * 64 + k8 * 8;
            dst = wp_pk + (size_t)c2 * 8;
        } else {                           // w_c 1024x768, KT=12
            const int c3 = cid - 131072;
            const int ml = c3 & 127, k8 = (c3 >> 7) & 7;
            const int ktmt = c3 >> 10;
            const int kt = ktmt % 12, mt = ktmt / 12;
            src = w_c + (size_t)(mt * 128 + ml) * 768 + kt * 64 + k8 * 8;
            dst = wc_pk + (size_t)c3 * 8;
        }
        const float4 v0 = *(const float4*)src, v1 = *(const float4*)(src + 4);
        unsigned short tmp[8];
        tmp[0] = f2bf(v0.x); tmp[1] = f2bf(v0.y); tmp[2] = f2bf(v0.z); tmp[3] = f2bf(v0.w);
        tmp[4] = f2bf(v1.x); tmp[5] = f2bf(v1.y); tmp[6] = f2bf(v1.z); tmp[7] = f2bf(v1.w);
        *(uint4*)dst = *(uint4*)tmp;
        return;
    }
    // pack cross input c [b][768][77] -> B layout per batch (KT=12, N padded to 128)
    const int idx2 = blockIdx.x - 1408;     // 192 = 12 kt * 16 b
    const int kt = idx2 % 12, b = idx2 / 12;
#pragma unroll
    for (int it = 0; it < 4; it++) {
        const int idx = it * 256 + tid;     // 1024 chunks per (kt,b)
        const int k8 = idx >> 7, l = idx & 127;
        unsigned short tmp[8];
        const float* src = cin + ((size_t)b * CD_ + kt * 64 + k8 * 8) * L_ + l;
#pragma unroll
        for (int q = 0; q < 8; q++)
            tmp[q] = (l < L_) ? f2bf(src[(size_t)q * L_]) : (unsigned short)0;
        *(uint4*)&cpk[(size_t)b * 98304 + ((size_t)(kt * 8 + k8)) * 1024 + (size_t)l * 8] =
            *(uint4*)tmp;
    }
}

// -------- GroupNorm apply + transpose + bf16 pack into GEMM-B layout --------
__global__ __launch_bounds__(256) void gn_apply_t(const float* __restrict__ x,
                                                  const float* __restrict__ stats,
                                                  const float* __restrict__ gamma,
                                                  const float* __restrict__ beta,
                                                  unsigned short* __restrict__ xnT) {
    const int t0 = blockIdx.x * 64, kt = blockIdx.y, b = blockIdx.z;
    const int c0 = kt * 64;
    const int tid = threadIdx.x;
    __shared__ float st[64][66];   // [t][c]
#pragma unroll
    for (int it = 0; it < 4; it++) {
        const int fid = it * 256 + tid;
        const int ci = fid >> 4, t4 = (fid & 15) * 4;
        const int c = c0 + ci;
        const float4 xv = *(const float4*)&x[((size_t)(b * C_ + c) << 10) + t0 + t4];
        const int bg = b * G_ + (c >> 4);
        const float mean = stats[2 * bg], istd = stats[2 * bg + 1];
        const float gs = gamma[c] * istd, gb = beta[c] - mean * gs;
        st[t4 + 0][ci] = xv.x * gs + gb;
        st[t4 + 1][ci] = xv.y * gs + gb;
        st[t4 + 2][ci] = xv.z * gs + gb;
        st[t4 + 3][ci] = xv.w * gs + gb;
    }
    __syncthreads();
#pragma unroll
    for (int it = 0; it < 2; it++) {
        const int cid = it * 256 + tid;
        const int k8 = cid >> 6, tl = cid & 63;
        const int n = (b << 10) + t0 + tl;
        const int nt = n >> 7, nm = n & 127;
        unsigned short tmp[8];
        const float* src = &st[tl][k8 * 8];
#pragma unroll
        for (int q = 0; q < 8; q++) tmp[q] = f2bf(src[q]);
        *(uint4*)&xnT[(((size_t)nt * 8 + kt) * 8 + k8) * 1024 + (size_t)nm * 8] = *(uint4*)tmp;
    }
}

// ---------------- MFMA bf16 GEMM, 128x128 tile, BK=64 ----------------
// MODE 0: qkv (KT=8)  -> packed-chunk Q(scaled)/K/V (+bias).
// MODE 1: proj (KT=8) -> fp32 out = C + bias + resid.
// MODE 2: cross (KT=12, batched z) -> Kc/Vc chunks at stiles 16/17, pad->0.
template<int MODE, int KT>
__global__ __launch_bounds__(256) void mgemm_k(const unsigned short* __restrict__ Apk,
                                               const unsigned short* __restrict__ Bpk,
                                               const float* __restrict__ bias,
                                               const float* __restrict__ resid,
                                               unsigned short* __restrict__ qpk,
                                               unsigned short* __restrict__ kpk,
                                               unsigned short* __restrict__ vpk,
                                               float* __restrict__ outp) {
    __shared__ unsigned short lds[18432];   // staging A[0,8192) B[8192,16384); V-epi 4x4608
    const int tid = threadIdx.x, wave = tid >> 6, lane = tid & 63;
    const int quad = lane >> 4, l16 = lane & 15;
    const int nt = blockIdx.x, mt = blockIdx.y;
    const int mw = (wave & 1) * 64, nw = (wave >> 1) * 64;

    f32x4 acc[4][4];
#pragma unroll
    for (int i = 0; i < 4; i++)
#pragma unroll
        for (int j = 0; j < 4; j++) acc[i][j] = (f32x4){0.f, 0.f, 0.f, 0.f};

    const unsigned short* Ab = Apk + (size_t)mt * KT * 8192;
    const unsigned short* Bb = Bpk + ((MODE == 2) ? (size_t)blockIdx.z * KT * 8192 : 0)
                                   + (size_t)nt * KT * 8192;

    for (int kt = 0; kt < KT; kt++) {
        const unsigned short* as = Ab + kt * 8192 + wave * 2048 + lane * 8;
        const unsigned short* bs = Bb + kt * 8192 + wave * 2048 + lane * 8;
        unsigned short* la = lds + wave * 2048;
        unsigned short* lb = lds + 8192 + wave * 2048;
#pragma unroll
        for (int j = 0; j < 4; j++) {
            gload_lds16(as + j * 512, la + j * 512);
            gload_lds16(bs + j * 512, lb + j * 512);
        }
        __syncthreads();
#pragma unroll
        for (int kh = 0; kh < 2; kh++) {
            const int k8 = kh * 4 + quad;
            bf16x8 af[4], bfr[4];
#pragma unroll
            for (int i = 0; i < 4; i++) {
                af[i]  = *(const bf16x8*)&lds[(size_t)(k8 * 128 + mw + i * 16 + l16) * 8];
                bfr[i] = *(const bf16x8*)&lds[8192 + (size_t)(k8 * 128 + nw + i * 16 + l16) * 8];
            }
#pragma unroll
            for (int mi = 0; mi < 4; mi++)
#pragma unroll
                for (int ni = 0; ni < 4; ni++)
                    acc[mi][ni] = __builtin_amdgcn_mfma_f32_16x16x32_bf16(
                        af[mi], bfr[ni], acc[mi][ni], 0, 0, 0);
        }
        __syncthreads();
    }

    const int gm0 = mt * 128 + mw;
    const int gn0 = nt * 128 + nw;

    if (MODE == 1) {
        const int b = gn0 >> 10, t0 = gn0 & 1023;
#pragma unroll
        for (int mi = 0; mi < 4; mi++) {
#pragma unroll
            for (int r = 0; r < 4; r++) {
                const int m = gm0 + mi * 16 + quad * 4 + r;
                const float bv = bias[m];
                const size_t rowb = ((size_t)(b * C_ + m) << 10) + t0;
#pragma unroll
                for (int ni = 0; ni < 4; ni++) {
                    const size_t a = rowb + ni * 16 + l16;
                    outp[a] = acc[mi][ni][r] + bv + resid[a];
                }
            }
        }
        return;
    }

    // regions are block-uniform (128-tile never straddles a 512 boundary)
    const int region = gm0 >> 9;              // MODE0: 0=Q 1=K 2=V ; MODE2: 0=Kc 1=Vc
    const int h = (gm0 & 511) >> 6;
    const int b = (MODE == 2) ? blockIdx.z : (gn0 >> 10);
    const int bh = b * 8 + h;
    const bool vregion = (MODE == 0) ? (region == 2) : (region == 1);

    if (!vregion) {
        // LDS-free packed-chunk writes for Q / K / Kc
        const float sc = (MODE == 0 && region == 0) ? QSC : 1.0f;
        unsigned short* base;
        int trow0;                            // token row base within stile, t64 base
        size_t tilestride;
        if (MODE == 0) {
            base = (region == 0) ? qpk + (size_t)bh * 16 * 4096
                                 : kpk + (size_t)bh * 18 * 4096;
            trow0 = gn0 & 1023;
        } else {
            base = kpk + (size_t)(bh * 18 + 16 + (gn0 >> 6)) * 4096;
            trow0 = -1;
        }
        (void)tilestride;
#pragma unroll
        for (int mi = 0; mi < 4; mi++) {
            const int k8 = mi * 2 + (quad >> 1);
            const int sub = (quad & 1) * 4;
#pragma unroll
            for (int ni = 0; ni < 4; ni++) {
                float vv[4];
                bool valid = true;
                if (MODE == 2) valid = (gn0 + ni * 16 + l16) < L_;
#pragma unroll
                for (int r = 0; r < 4; r++)
                    vv[r] = valid ? (acc[mi][ni][r] + bias[gm0 + mi * 16 + quad * 4 + r]) * sc
                                  : 0.f;
                uint2 d;
                d.x = pk_bf16(vv[0], vv[1]);
                d.y = pk_bf16(vv[2], vv[3]);
                unsigned short* dst;
                if (MODE == 0) {
                    const int t = trow0 + ni * 16 + l16;
                    dst = base + (size_t)(t >> 6) * 4096 + ((size_t)k8 * 64 + (t & 63)) * 8 + sub;
                } else {
                    const int row = ni * 16 + l16;
                    dst = base + ((size_t)k8 * 64 + row) * 8 + sub;
                }
                *(uint2*)dst = d;
            }
        }
    } else {
        // V: LDS transpose then chunk stores (chunks are 8 s-values per ch)
        unsigned short* wlds = lds + wave * 4608;   // 64 ch x 72
#pragma unroll
        for (int mi = 0; mi < 4; mi++)
#pragma unroll
            for (int ni = 0; ni < 4; ni++) {
                bool valid = true;
                if (MODE == 2) valid = (gn0 + ni * 16 + l16) < L_;
#pragma unroll
                for (int r = 0; r < 4; r++) {
                    const float v = valid ? acc[mi][ni][r] + bias[gm0 + mi * 16 + quad * 4 + r]
                                          : 0.f;
                    wlds[(mi * 16 + quad * 4 + r) * SROW + ni * 16 + l16] = f2bf(v);
                }
            }
        __syncthreads();
        const int stile = (MODE == 0) ? ((gn0 & 1023) >> 6) : (16 + (gn0 >> 6));
        unsigned short* dst = vpk + (size_t)(bh * 18 + stile) * 4096;
        const int sk8 = lane & 7, cb = lane >> 3;
#pragma unroll
        for (int it = 0; it < 8; it++) {
            const int ch = it * 8 + cb;
            *(uint4*)&dst[((size_t)sk8 * 64 + ch) * 8] =
                *(const uint4*)&wlds[ch * SROW + sk8 * 8];
        }
    }
}

// ---------------- Flash attention (swapped-operand QK^T, exp2, no max) ----------------
// Grid (bh=128, qt=16). A=K B=Q -> lane holds S[t=l16][s=quad*4+r] (s-contiguous!).
__global__ __launch_bounds__(256) void flash_k(const unsigned short* __restrict__ qpk,
                                               const unsigned short* __restrict__ kpk,
                                               const unsigned short* __restrict__ vpk,
                                               unsigned short* __restrict__ aT) {
    __shared__ __align__(16) unsigned short ks[4096];
    __shared__ __align__(16) unsigned short vs[4096];
    __shared__ __align__(16) unsigned short psA[4 * 16 * SROW];

    const int tid  = threadIdx.x;
    const int wave = tid >> 6, lane = tid & 63;
    const int quad = lane >> 4, l16 = lane & 15;
    const int bh  = blockIdx.x;
    const int b = bh >> 3, h = bh & 7;
    const int qt0 = blockIdx.y * 64;

    // Q B-frags straight from global (token = qt0 + wave*16 + l16)
    const unsigned short* qtb = qpk + ((size_t)bh * 16 + blockIdx.y) * 4096;
    const int qrow = wave * 16 + l16;
    const bf16x8 bq0 = *(const bf16x8*)&qtb[((size_t)quad * 64 + qrow) * 8];
    const bf16x8 bq1 = *(const bf16x8*)&qtb[((size_t)(quad + 4) * 64 + qrow) * 8];

    unsigned short* ps = psA + wave * 16 * SROW;

    float rsum = 0.f;
    f32x4 o_acc[4];
#pragma unroll
    for (int nb = 0; nb < 4; nb++) o_acc[nb] = (f32x4){0.f, 0.f, 0.f, 0.f};

    for (int stile = 0; stile < 18; stile++) {
        const unsigned short* kt = kpk + ((size_t)bh * 18 + stile) * 4096 + wave * 1024 + lane * 8;
        const unsigned short* vt = vpk + ((size_t)bh * 18 + stile) * 4096 + wave * 1024 + lane * 8;
        unsigned short* lk = ks + wave * 1024;
        unsigned short* lv = vs + wave * 1024;
        gload_lds16(kt, lk);       gload_lds16(kt + 512, lk + 512);
        gload_lds16(vt, lv);       gload_lds16(vt + 512, lv + 512);
        __syncthreads();

        // QK^T: A = K rows (sb*16+l16), B = Q -> sacc[sb] = S[t=l16][s=sb*16+quad*4+r]
        f32x4 sacc[4];
#pragma unroll
        for (int sb = 0; sb < 4; sb++) {
            const bf16x8 ak0 = *(const bf16x8*)&ks[((size_t)quad * 64 + sb * 16 + l16) * 8];
            const bf16x8 ak1 = *(const bf16x8*)&ks[((size_t)(quad + 4) * 64 + sb * 16 + l16) * 8];
            f32x4 z = (f32x4){0.f, 0.f, 0.f, 0.f};
            z = __builtin_amdgcn_mfma_f32_16x16x32_bf16(ak0, bq0, z, 0, 0, 0);
            z = __builtin_amdgcn_mfma_f32_16x16x32_bf16(ak1, bq1, z, 0, 0, 0);
            sacc[sb] = z;
        }

        // exp2, scalar l accumulate, pk-pack, ONE b64 LDS write per sb
#pragma unroll
        for (int sb = 0; sb < 4; sb++) {
            const float e0 = __builtin_exp2f(sacc[sb][0]);
            const float e1 = __builtin_exp2f(sacc[sb][1]);
            const float e2 = __builtin_exp2f(sacc[sb][2]);
            const float e3 = __builtin_exp2f(sacc[sb][3]);
            rsum += (e0 + e1) + (e2 + e3);
            uint2 d;
            d.x = pk_bf16(e0, e1);
            d.y = pk_bf16(e2, e3);
            *(uint2*)&ps[l16 * SROW + sb * 16 + quad * 4] = d;
        }
        asm volatile("s_waitcnt lgkmcnt(0)" ::: "memory");

        // PV: A = P[t=l16][s=quad*8+j], B = V chunks
        const bf16x8 ap0 = *(const bf16x8*)&ps[l16 * SROW + quad * 8];
        const bf16x8 ap1 = *(const bf16x8*)&ps[l16 * SROW + 32 + quad * 8];
#pragma unroll
        for (int nb = 0; nb < 4; nb++) {
            const bf16x8 bv0 = *(const bf16x8*)&vs[((size_t)quad * 64 + nb * 16 + l16) * 8];
            const bf16x8 bv1 = *(const bf16x8*)&vs[((size_t)(quad + 4) * 64 + nb * 16 + l16) * 8];
            o_acc[nb] = __builtin_amdgcn_mfma_f32_16x16x32_bf16(ap0, bv0, o_acc[nb], 0, 0, 0);
            o_acc[nb] = __builtin_amdgcn_mfma_f32_16x16x32_bf16(ap1, bv1, o_acc[nb], 0, 0, 0);
        }
        __syncthreads();
    }

    // l[t=l16]: reduce partial sums across the 4 quads, correct for pad tokens
    float lsum = rsum;
    lsum += __shfl_xor(lsum, 16);
    lsum += __shfl_xor(lsum, 32);
    float linv[4];
#pragma unroll
    for (int r = 0; r < 4; r++) {
        const float lr = __shfl(lsum, quad * 4 + r);   // l for t = quad*4+r
        linv[r] = 1.0f / (lr - (float)NPAD);
    }

    // epilogue: O[t=quad*4+r][ch=nb*16+l16] -> stage [t][ch] -> aT packed-B chunks
#pragma unroll
    for (int nb = 0; nb < 4; nb++)
#pragma unroll
        for (int r = 0; r < 4; r++)
            ps[(quad * 4 + r) * SROW + nb * 16 + l16] = f2bf(o_acc[nb][r] * linv[r]);
    asm volatile("s_waitcnt lgkmcnt(0)" ::: "memory");
    const int k8 = lane >> 3;
#pragma unroll
    for (int it = 0; it < 2; it++) {
        const int tl = (lane & 7) + it * 8;
        const int n = (b << 10) + qt0 + wave * 16 + tl;
        const int ntb = n >> 7, nm = n & 127;
        *(uint4*)&aT[(((size_t)ntb * 8 + h) * 8 + k8) * 1024 + (size_t)nm * 8] =
            *(const uint4*)&ps[tl * SROW + k8 * 8];
    }
}

// ---------------- Launch ----------------
extern "C" void kernel_launch(void* const* d_in, const int* in_sizes, int n_in,
                              void* d_out, int out_size, void* d_ws, size_t ws_size,
                              hipStream_t stream) {
    const float* x     = (const float*)d_in[0];
    const float* cin   = (const float*)d_in[1];
    const float* gamma = (const float*)d_in[2];
    const float* beta  = (const float*)d_in[3];
    const float* w_qkv = (const float*)d_in[4];
    const float* b_qkv = (const float*)d_in[5];
    const float* w_c   = (const float*)d_in[6];
    const float* b_c   = (const float*)d_in[7];
    const float* w_p   = (const float*)d_in[8];
    const float* b_p   = (const float*)d_in[9];
    float* out = (float*)d_out;

    float* ws    = (float*)d_ws;
    float* stats = ws;                                        // 1,024 f
    unsigned short* xnT     = (unsigned short*)(ws + 1024);   // 8,388,608 us
    unsigned short* wqkv_pk = xnT + 8388608;                  // 786,432 us
    unsigned short* wp_pk   = wqkv_pk + 786432;               // 262,144 us
    unsigned short* wc_pk   = wp_pk + 262144;                 // 786,432 us
    unsigned short* cpk     = wc_pk + 786432;                 // 1,572,864 us
    unsigned short* qpk     = cpk + 1572864;                  // 8,388,608 us
    unsigned short* kpk     = qpk + 8388608;                  // 9,437,184 us
    unsigned short* vpk     = kpk + 9437184;                  // 9,437,184 us
    unsigned short* aT      = vpk + 9437184;                  // 8,388,608 us
    // total ~95 MB

    prep_k<<<dim3(1600), 256, 0, stream>>>(x, stats, w_qkv, w_p, w_c, cin,
                                           wqkv_pk, wp_pk, wc_pk, cpk);
    gn_apply_t<<<dim3(16, 8, 16), 256, 0, stream>>>(x, stats, gamma, beta, xnT);
    // qkv MFMA GEMM -> packed-chunk qpk (scaled) / kpk / vpk
    mgemm_k<0, 8><<<dim3(128, 12), 256, 0, stream>>>(wqkv_pk, xnT, b_qkv, nullptr,
                                                     qpk, kpk, vpk, nullptr);
    // cross MFMA GEMM -> kpk/vpk stiles 16,17 (zero pad)
    mgemm_k<2, 12><<<dim3(1, 8, 16), 256, 0, stream>>>(wc_pk, cpk, b_c, nullptr,
                                                       nullptr, kpk, vpk, nullptr);
    // flash attention -> aT (packed B layout for proj)
    flash_k<<<dim3(128, 16), 256, 0, stream>>>(qpk, kpk, vpk, aT);
    // proj MFMA GEMM + bias + residual -> out
    mgemm_k<1, 8><<<dim3(128, 4), 256, 0, stream>>>(wp_pk, aT, b_p, x,
                                                    nullptr, nullptr, nullptr, out);
}